// Round 2
// baseline (11232.007 us; speedup 1.0000x reference)
//
#include <hip/hip_runtime.h>
#include <stdint.h>

// V=32000, E=256, H=512, S=128, B=32, T=32

using short8 = __attribute__((ext_vector_type(8))) short;
using f32x4  = __attribute__((ext_vector_type(4))) float;

__device__ __forceinline__ short f2bf(float x){
  unsigned u = __float_as_uint(x);
  unsigned r = (u + 0x7fffu + ((u >> 16) & 1u)) >> 16;
  return (short)(unsigned short)r;
}
__device__ __forceinline__ float sigmf(float x){ return 1.0f/(1.0f + __expf(-x)); }
__device__ __forceinline__ float fast_tanh(float x){
  const float e = __expf(2.0f*x);
  return 1.0f - 2.0f/(e + 1.0f);      // exact at +-inf, ~1e-7 rel error
}

// device-scope sense barrier among n blocks (generation counter)
__device__ __forceinline__ void grid_bar(unsigned* cnt, unsigned* gen, unsigned n){
  __syncthreads();
  if (threadIdx.x == 0){
    unsigned g = __hip_atomic_load(gen, __ATOMIC_RELAXED, __HIP_MEMORY_SCOPE_AGENT);
    unsigned a = __hip_atomic_fetch_add(cnt, 1u, __ATOMIC_ACQ_REL, __HIP_MEMORY_SCOPE_AGENT);
    if (a == n - 1u){
      __hip_atomic_store(cnt, 0u, __ATOMIC_RELAXED, __HIP_MEMORY_SCOPE_AGENT);
      __hip_atomic_fetch_add(gen, 1u, __ATOMIC_ACQ_REL, __HIP_MEMORY_SCOPE_AGENT);
    } else {
      while (__hip_atomic_load(gen, __ATOMIC_ACQUIRE, __HIP_MEMORY_SCOPE_AGENT) == g){
        __builtin_amdgcn_s_sleep(8);
      }
    }
  }
  __syncthreads();
}

// ---------------------------------------------------------------------------
__global__ void k_zero(float* __restrict__ p, int n){
  int i = blockIdx.x*256 + threadIdx.x;
  const int stride = gridDim.x*256;
  for (; i < n; i += stride) p[i] = 0.f;
}

// ---------------------------------------------------------------------------
__global__ __launch_bounds__(256) void k_gather(
    const int* __restrict__ src, const int* __restrict__ trg,
    const float* __restrict__ embed,
    short* __restrict__ emb_src_bf, short* __restrict__ emb_trg_bf)
{
  const int row = blockIdx.x, tid = threadIdx.x;
  if (row < 4096){
    const int tok = src[row];
    emb_src_bf[(size_t)row*256 + tid] = f2bf(embed[(size_t)tok*256 + tid]);
  } else {
    const int r = row - 4096;
    short v = 0;
    if (r < 992){ const int tok = trg[r]; v = f2bf(embed[(size_t)tok*256 + tid]); }
    emb_trg_bf[(size_t)r*256 + tid] = v;
  }
}

// ---------------------------------------------------------------------------
// MFMA GEMM: C[M,N] f32 = A_bf16[M,lda] @ W_f32[N,ldw]^T + bias0 + bias1
__global__ __launch_bounds__(256) void k_gemm_aw(
    const short* __restrict__ A, int lda,
    const float* __restrict__ W, int ldw,
    float* __restrict__ C, int ldc,
    const float* __restrict__ bias0, const float* __restrict__ bias1,
    int Mvalid, int K)
{
  __shared__ __align__(16) short As[128*32];
  __shared__ __align__(16) short Bs[128*32];
  const int tid = threadIdx.x;
  const int bm = blockIdx.x, bn = blockIdx.y;
  const int w  = tid >> 6,  l  = tid & 63;
  const int wm = w >> 1,    wn = w & 1;
  const int lr = l & 15,    lk = l >> 4;

  const int r0 = tid >> 2;
  const int s0 = (tid & 3) << 3;
  const int r1 = r0 + 64;

  const short* a0 = A + (size_t)(bm*128 + r0)*lda + s0;
  const short* a1 = A + (size_t)(bm*128 + r1)*lda + s0;
  const float* w0 = W + (size_t)(bn*128 + r0)*ldw + s0;
  const float* w1 = W + (size_t)(bn*128 + r1)*ldw + s0;

  const f32x4 zero4 = {0.f,0.f,0.f,0.f};
  f32x4 acc[4][4];
  #pragma unroll
  for (int mi=0;mi<4;mi++){
    #pragma unroll
    for (int ni=0;ni<4;ni++) acc[mi][ni] = zero4;
  }

  for (int k0 = 0; k0 < K; k0 += 32){
    short8 va0 = *(const short8*)(a0 + k0);
    short8 va1 = *(const short8*)(a1 + k0);
    float4 f00 = *(const float4*)(w0 + k0);
    float4 f01 = *(const float4*)(w0 + k0 + 4);
    float4 f10 = *(const float4*)(w1 + k0);
    float4 f11 = *(const float4*)(w1 + k0 + 4);
    short8 vb0, vb1;
    vb0[0]=f2bf(f00.x); vb0[1]=f2bf(f00.y); vb0[2]=f2bf(f00.z); vb0[3]=f2bf(f00.w);
    vb0[4]=f2bf(f01.x); vb0[5]=f2bf(f01.y); vb0[6]=f2bf(f01.z); vb0[7]=f2bf(f01.w);
    vb1[0]=f2bf(f10.x); vb1[1]=f2bf(f10.y); vb1[2]=f2bf(f10.z); vb1[3]=f2bf(f10.w);
    vb1[4]=f2bf(f11.x); vb1[5]=f2bf(f11.y); vb1[6]=f2bf(f11.z); vb1[7]=f2bf(f11.w);

    __syncthreads();
    *((short8*)As + tid)       = va0;
    *((short8*)As + tid + 256) = va1;
    *((short8*)Bs + tid)       = vb0;
    *((short8*)Bs + tid + 256) = vb1;
    __syncthreads();

    short8 af[4], bfr[4];
    #pragma unroll
    for (int mi=0;mi<4;mi++) af[mi]  = *(const short8*)&As[(wm*64 + mi*16 + lr)*32 + (lk<<3)];
    #pragma unroll
    for (int ni=0;ni<4;ni++) bfr[ni] = *(const short8*)&Bs[(wn*64 + ni*16 + lr)*32 + (lk<<3)];
    #pragma unroll
    for (int mi=0;mi<4;mi++){
      #pragma unroll
      for (int ni=0;ni<4;ni++)
        acc[mi][ni] = __builtin_amdgcn_mfma_f32_16x16x32_bf16(af[mi], bfr[ni], acc[mi][ni], 0,0,0);
    }
  }

  #pragma unroll
  for (int mi=0;mi<4;mi++){
    const int rb = bm*128 + wm*64 + mi*16 + (lk<<2);
    #pragma unroll
    for (int ni=0;ni<4;ni++){
      const int col = bn*128 + wn*64 + ni*16 + lr;
      float bv = 0.f;
      if (bias0) bv += bias0[col];
      if (bias1) bv += bias1[col];
      #pragma unroll
      for (int r=0;r<4;r++){
        const int row = rb + r;
        if (row < Mvalid) C[(size_t)row*ldc + col] = acc[mi][ni][r] + bv;
      }
    }
  }
}

// ---------------------------------------------------------------------------
// WT[k][c] = attnW[c][k] for c,k < 512 (query-projection weight, transposed)
__global__ __launch_bounds__(256) void k_transpose512(
    const float* __restrict__ A, float* __restrict__ AT)
{
  __shared__ float t[64][65];
  const int tid = threadIdx.x;
  const int kt = blockIdx.x & 7, ct = blockIdx.x >> 3;
  const int c0 = ct*64, k0 = kt*64;
  for (int i = tid; i < 1024; i += 256){
    const int r = i >> 4, q = i & 15;
    float4 v = *(const float4*)&A[(size_t)(c0+r)*1024 + k0 + (q<<2)];
    t[r][(q<<2)+0]=v.x; t[r][(q<<2)+1]=v.y; t[r][(q<<2)+2]=v.z; t[r][(q<<2)+3]=v.w;
  }
  __syncthreads();
  for (int i = tid; i < 1024; i += 256){
    const int r = i >> 4, q = i & 15;
    float4 v;
    v.x = t[(q<<2)+0][r]; v.y = t[(q<<2)+1][r];
    v.z = t[(q<<2)+2][r]; v.w = t[(q<<2)+3][r];
    *(float4*)&AT[(size_t)(k0+r)*512 + c0 + (q<<2)] = v;
  }
}

// ---------------------------------------------------------------------------
// helpers for persistent recurrent kernels
__device__ __forceinline__ void stage32x512(float* __restrict__ lds, const float* __restrict__ src){
  #pragma unroll
  for (int i = 0; i < 16; ++i){
    const int idx = threadIdx.x + (i << 8);
    const int bb = idx >> 7, jj = idx & 127;
    *(float4*)&lds[bb*516 + (jj<<2)] = *(const float4*)&src[(bb<<9) + (jj<<2)];
  }
}
__device__ __forceinline__ float2 dot2_512(const float* __restrict__ hx,
                                           const float* __restrict__ wA,
                                           const float* __restrict__ wB){
  f32x4 sA = {0.f,0.f,0.f,0.f}, sB = {0.f,0.f,0.f,0.f};
  #pragma unroll 4
  for (int q = 0; q < 512; q += 4){
    const float4 hv = *(const float4*)&hx[q];
    const float4 wa = *(const float4*)&wA[q];
    const float4 wb = *(const float4*)&wB[q];
    sA.x = fmaf(wa.x, hv.x, sA.x); sA.y = fmaf(wa.y, hv.y, sA.y);
    sA.z = fmaf(wa.z, hv.z, sA.z); sA.w = fmaf(wa.w, hv.w, sA.w);
    sB.x = fmaf(wb.x, hv.x, sB.x); sB.y = fmaf(wb.y, hv.y, sB.y);
    sB.z = fmaf(wb.z, hv.z, sB.z); sB.w = fmaf(wb.w, hv.w, sB.w);
  }
  return make_float2((sA.x+sA.y)+(sA.z+sA.w), (sB.x+sB.y)+(sB.z+sB.w));
}

// ---------------------------------------------------------------------------
// persistent bidirectional encoder: 256 blocks (dir = bid&1, m = bid>>1).
// block owns k-slice [4m,4m+4) of all 4 gates; c register-resident.
__global__ __launch_bounds__(256,1) void k_enc_persist(
    const float* __restrict__ pre_f, const float* __restrict__ pre_b,
    const float* __restrict__ Whh_f, const float* __restrict__ Whh_b,
    float* __restrict__ f_outs, float* __restrict__ b_outs,
    float* __restrict__ c_f_out, float* __restrict__ c_b_out,
    unsigned* __restrict__ bars)
{
  __shared__ __align__(16) float h_lds[32*516];
  __shared__ float zbuf[16*32];
  const int bid = blockIdx.x;
  const int dir = bid & 1;
  const int m   = bid >> 1;
  const float* pre = dir ? pre_b : pre_f;
  const float* Whh = dir ? Whh_b : Whh_f;
  float* outs  = dir ? b_outs : f_outs;
  float* c_out = dir ? c_b_out : c_f_out;
  unsigned* cnt = bars + (dir ? 32 : 0);
  unsigned* gen = cnt + 16;

  const int tid = threadIdx.x;
  const int b = tid & 31, r = tid >> 5;       // r in 0..7
  const int k0 = m*4;
  const int jA = ((r>>2)<<9) + k0 + (r&3);    // gates 0/1
  const int jB = jA + 1024;                   // gates 2/3
  const float* wA = Whh + (size_t)jA*512;
  const float* wB = Whh + (size_t)jB*512;

  const int b2 = tid & 31, k2c = (tid >> 5) & 3;  // for tid<128
  float c_reg = 0.f;

  for (int t = 0; t < 128; ++t){
    if (t == 0){
      #pragma unroll
      for (int i = 0; i < 16; ++i){
        const int idx = tid + (i << 8);
        const int bb = idx >> 7, jj = idx & 127;
        *(float4*)&h_lds[bb*516 + (jj<<2)] = make_float4(0.f,0.f,0.f,0.f);
      }
    } else {
      stage32x512(h_lds, outs + (size_t)(t-1)*16384);
    }
    __syncthreads();

    const float* pr = pre + (size_t)(dir ? (127-t) : t)*65536;
    const float2 d = dot2_512(&h_lds[b*516], wA, wB);
    const float accA = pr[b*2048 + jA] + d.x;
    const float accB = pr[b*2048 + jB] + d.y;
    zbuf[(r<<5) + b]       = accA;
    zbuf[((r+8)<<5) + b]   = accB;
    __syncthreads();

    if (tid < 128){
      const float zi = zbuf[((0+k2c)<<5) + b2];
      const float zf = zbuf[((4+k2c)<<5) + b2];
      const float zg = zbuf[((8+k2c)<<5) + b2];
      const float zo = zbuf[((12+k2c)<<5) + b2];
      const float cn = sigmf(zf)*c_reg + sigmf(zi)*fast_tanh(zg);
      c_reg = cn;
      outs[(size_t)t*16384 + b2*512 + k0 + k2c] = sigmf(zo)*fast_tanh(cn);
    }
    grid_bar(cnt, gen, 128u);
  }
  if (tid < 128) c_out[b2*512 + k0 + k2c] = c_reg;
}

// ---------------------------------------------------------------------------
__global__ __launch_bounds__(256) void k_sum_enc(
    const float* __restrict__ f_outs, const float* __restrict__ b_outs,
    float* __restrict__ enc_sum, short* __restrict__ enc_sum_bf)
{
  const int i = blockIdx.x*256 + threadIdx.x;
  const int s = i >> 14, rem = i & 16383;
  const float v = f_outs[i] + b_outs[(size_t)(127 - s)*16384 + rem];
  enc_sum[i] = v;
  enc_sum_bf[i] = f2bf(v);
}

// ---------------------------------------------------------------------------
// persistent decoder: 128 blocks; 3 phases/step; c0/c1 register-resident.
__global__ __launch_bounds__(256,1) void k_dec_persist(
    const float* __restrict__ demb,      // [1024][2048] incl. bih0+bhh0
    const float* __restrict__ Wih0c,     // dWih0+256 (ld 768)
    const float* __restrict__ Whh0,
    const float* __restrict__ Wih1,
    const float* __restrict__ Whh1,
    const float* __restrict__ bih1, const float* __restrict__ bhh1,
    const float* __restrict__ WT,        // [512][512] qproj weights^T
    const float* __restrict__ attnV,
    const float* __restrict__ enc_proj,  // [4096][512] incl. attn_b
    const float* __restrict__ enc_sum,   // [4096][512]
    const float* __restrict__ h0_init, const float* __restrict__ h1_init,
    const float* __restrict__ c0_init, const float* __restrict__ c1_init,
    float* __restrict__ h0buf, float* __restrict__ h1buf,   // [2][32][512]
    float* __restrict__ ctxb,                               // [32][512]
    short* __restrict__ h1ctx,                              // [31][32][1024] bf16
    unsigned* __restrict__ bars)
{
  __shared__ __align__(16) float x_lds[32*516];
  __shared__ float zbuf[16*32];
  __shared__ __align__(16) float q_h[512], q_s[512], v_s[512];
  __shared__ float part[256], aw[128], red[128];

  const int bid = blockIdx.x, tid = threadIdx.x;
  unsigned* cnt = bars + 64;
  unsigned* gen = bars + 80;

  const int b = tid & 31, r = tid >> 5;
  const int k0 = bid*4;
  const int jA = ((r>>2)<<9) + k0 + (r&3);
  const int jB = jA + 1024;
  const int b2 = tid & 31, k2c = (tid >> 5) & 3;

  float c0_reg = 0.f, c1_reg = 0.f;
  if (tid < 128){
    c0_reg = c0_init[b2*512 + k0 + k2c];
    c1_reg = c1_init[b2*512 + k0 + k2c];
  }

  for (int t = 0; t < 31; ++t){
    // ---------- Phase A: attention (blocks 0..31, b = bid) ----------
    if (bid < 32){
      const int ab = bid;
      const float* h1src = (t == 0 ? h1_init : h1buf + (size_t)(t&1)*16384) + ab*512;
      if (tid < 128){
        ((float4*)q_h)[tid] = ((const float4*)h1src)[tid];
        ((float4*)v_s)[tid] = ((const float4*)attnV)[tid];
      }
      __syncthreads();
      {
        float a0 = 0.f, a1 = 0.f;
        const float2* wt2 = (const float2*)WT;
        #pragma unroll 4
        for (int k = 0; k < 512; ++k){
          const float2 wv = wt2[k*256 + tid];
          const float hq = q_h[k];
          a0 = fmaf(hq, wv.x, a0); a1 = fmaf(hq, wv.y, a1);
        }
        q_s[2*tid] = a0; q_s[2*tid+1] = a1;
      }
      __syncthreads();
      {
        const int s = tid >> 1, half = tid & 1;
        const float* ep = enc_proj + ((size_t)(s*32 + ab))*512 + (half << 8);
        const float* qh = q_s + (half << 8);
        const float* vh = v_s + (half << 8);
        float p = 0.f;
        for (int kk = 0; kk < 256; kk += 4){
          const float4 e = *(const float4*)&ep[kk];
          p += fast_tanh(qh[kk+0] + e.x) * vh[kk+0];
          p += fast_tanh(qh[kk+1] + e.y) * vh[kk+1];
          p += fast_tanh(qh[kk+2] + e.z) * vh[kk+2];
          p += fast_tanh(qh[kk+3] + e.w) * vh[kk+3];
        }
        part[tid] = p;
      }
      __syncthreads();
      if (tid < 128){ const float sc = part[2*tid] + part[2*tid+1]; aw[tid] = sc; red[tid] = sc; }
      __syncthreads();
      for (int off = 64; off > 0; off >>= 1){
        if (tid < off) red[tid] = fmaxf(red[tid], red[tid+off]);
        __syncthreads();
      }
      const float mx = red[0];
      __syncthreads();
      if (tid < 128){ const float e = __expf(aw[tid] - mx); aw[tid] = e; red[tid] = e; }
      __syncthreads();
      for (int off = 64; off > 0; off >>= 1){
        if (tid < off) red[tid] += red[tid+off];
        __syncthreads();
      }
      const float inv = 1.0f / red[0];
      if (tid < 128) aw[tid] *= inv;
      __syncthreads();
      {
        const int cc = tid << 1;
        float x0 = 0.f, x1 = 0.f;
        for (int s = 0; s < 128; ++s){
          const float a = aw[s];
          const float* er = enc_sum + ((size_t)(s*32 + ab))*512 + cc;
          x0 = fmaf(a, er[0], x0);
          x1 = fmaf(a, er[1], x1);
        }
        ctxb[ab*512 + cc]     = x0;
        ctxb[ab*512 + cc + 1] = x1;
        h1ctx[(size_t)t*32768 + ab*1024 + 512 + cc]     = f2bf(x0);
        h1ctx[(size_t)t*32768 + ab*1024 + 512 + cc + 1] = f2bf(x1);
      }
    }
    grid_bar(cnt, gen, 128u);

    // ---------- Phase B: cell0 ----------
    {
      stage32x512(x_lds, ctxb);
      __syncthreads();
      float accA = demb[(size_t)t*65536 + b*2048 + jA];
      float accB = demb[(size_t)t*65536 + b*2048 + jB];
      {
        const float2 d = dot2_512(&x_lds[b*516], Wih0c + (size_t)jA*768, Wih0c + (size_t)jB*768);
        accA += d.x; accB += d.y;
      }
      __syncthreads();
      stage32x512(x_lds, t == 0 ? h0_init : h0buf + (size_t)(t&1)*16384);
      __syncthreads();
      {
        const float2 d = dot2_512(&x_lds[b*516], Whh0 + (size_t)jA*512, Whh0 + (size_t)jB*512);
        accA += d.x; accB += d.y;
      }
      zbuf[(r<<5) + b]     = accA;
      zbuf[((r+8)<<5) + b] = accB;
      __syncthreads();
      if (tid < 128){
        const float zi = zbuf[((0+k2c)<<5) + b2];
        const float zf = zbuf[((4+k2c)<<5) + b2];
        const float zg = zbuf[((8+k2c)<<5) + b2];
        const float zo = zbuf[((12+k2c)<<5) + b2];
        const float cn = sigmf(zf)*c0_reg + sigmf(zi)*fast_tanh(zg);
        c0_reg = cn;
        h0buf[(size_t)((t+1)&1)*16384 + b2*512 + k0 + k2c] = sigmf(zo)*fast_tanh(cn);
      }
    }
    grid_bar(cnt, gen, 128u);

    // ---------- Phase C: cell1 ----------
    {
      stage32x512(x_lds, h0buf + (size_t)((t+1)&1)*16384);
      __syncthreads();
      float accA = bih1[jA] + bhh1[jA];
      float accB = bih1[jB] + bhh1[jB];
      {
        const float2 d = dot2_512(&x_lds[b*516], Wih1 + (size_t)jA*512, Wih1 + (size_t)jB*512);
        accA += d.x; accB += d.y;
      }
      __syncthreads();
      stage32x512(x_lds, t == 0 ? h1_init : h1buf + (size_t)(t&1)*16384);
      __syncthreads();
      {
        const float2 d = dot2_512(&x_lds[b*516], Whh1 + (size_t)jA*512, Whh1 + (size_t)jB*512);
        accA += d.x; accB += d.y;
      }
      zbuf[(r<<5) + b]     = accA;
      zbuf[((r+8)<<5) + b] = accB;
      __syncthreads();
      if (tid < 128){
        const float zi = zbuf[((0+k2c)<<5) + b2];
        const float zf = zbuf[((4+k2c)<<5) + b2];
        const float zg = zbuf[((8+k2c)<<5) + b2];
        const float zo = zbuf[((12+k2c)<<5) + b2];
        const float cn = sigmf(zf)*c1_reg + sigmf(zi)*fast_tanh(zg);
        c1_reg = cn;
        const float hn = sigmf(zo)*fast_tanh(cn);
        h1buf[(size_t)((t+1)&1)*16384 + b2*512 + k0 + k2c] = hn;
        h1ctx[(size_t)t*32768 + b2*1024 + k0 + k2c] = f2bf(hn);
      }
    }
    grid_bar(cnt, gen, 128u);
  }
}

// ---------------------------------------------------------------------------
__global__ __launch_bounds__(256) void k_logsm(float* __restrict__ out){
  float* row = out + (size_t)blockIdx.x * 32000;
  const int tid = threadIdx.x;
  __shared__ float red[256];
  float m = -3.4e38f;
  for (int i = tid; i < 32000; i += 256) m = fmaxf(m, row[i]);
  red[tid] = m; __syncthreads();
  for (int off = 128; off > 0; off >>= 1){
    if (tid < off) red[tid] = fmaxf(red[tid], red[tid+off]);
    __syncthreads();
  }
  m = red[0]; __syncthreads();
  float s = 0.f;
  for (int i = tid; i < 32000; i += 256) s += __expf(row[i] - m);
  red[tid] = s; __syncthreads();
  for (int off = 128; off > 0; off >>= 1){
    if (tid < off) red[tid] += red[tid+off];
    __syncthreads();
  }
  const float lse = m + __logf(red[0]);
  for (int i = tid; i < 32000; i += 256) row[i] -= lse;
}

// ---------------------------------------------------------------------------
extern "C" void kernel_launch(void* const* d_in, const int* in_sizes, int n_in,
                              void* d_out, int out_size, void* d_ws, size_t ws_size,
                              hipStream_t stream)
{
  (void)in_sizes; (void)n_in; (void)out_size; (void)ws_size;
  const int*   src   = (const int*)d_in[0];
  const int*   trg   = (const int*)d_in[1];
  const float* embed = (const float*)d_in[2];
  const float* eWihF = (const float*)d_in[3];
  const float* eWhhF = (const float*)d_in[4];
  const float* ebihF = (const float*)d_in[5];
  const float* ebhhF = (const float*)d_in[6];
  const float* eWihB = (const float*)d_in[7];
  const float* eWhhB = (const float*)d_in[8];
  const float* ebihB = (const float*)d_in[9];
  const float* ebhhB = (const float*)d_in[10];
  const float* attnW = (const float*)d_in[11];
  const float* attnB = (const float*)d_in[12];
  const float* attnV = (const float*)d_in[13];
  const float* dWih0 = (const float*)d_in[14];
  const float* dWhh0 = (const float*)d_in[15];
  const float* dbih0 = (const float*)d_in[16];
  const float* dbhh0 = (const float*)d_in[17];
  const float* dWih1 = (const float*)d_in[18];
  const float* dWhh1 = (const float*)d_in[19];
  const float* dbih1 = (const float*)d_in[20];
  const float* dbhh1 = (const float*)d_in[21];
  const float* outW  = (const float*)d_in[22];
  const float* outB  = (const float*)d_in[23];

  float* out = (float*)d_out;
  // d_out scratch (all regions dead before final GEMM writes)
  float* enc_in_f = out;               // [128][32][2048]
  float* enc_in_b = out + 8388608;
  float* enc_sum  = out + 16777216;    // [128][32][512]
  float* enc_proj = out + 18874368;    // [4096][512]
  float* f_outs   = out + 20971520;    // [128][32][512]
  float* b_outs   = out + 23068672;
  float* demb     = out + 25165824;    // [1024][2048]
  short* emb_src_bf = (short*)(out + 27262976);
  short* emb_trg_bf = (short*)(out + 27787264);
  short* enc_sum_bf = (short*)(out + 27918336);
  float* WT         = out + 28966912;  // [512][512]

  char* ws = (char*)d_ws;
  short* h1ctx = (short*)ws;           // [1024][1024] bf16 region (2 MB)
  float* st    = (float*)(ws + 2097152);
  float* h0buf = st;                   // [2][32][512]
  float* h1buf = st + 32768;
  float* ctxb  = st + 65536;           // [32][512]
  float* c_f   = st + 81920;
  float* c_b   = st + 98304;
  unsigned* bars = (unsigned*)(st + 114688);   // 128 uints

  // 1. zero barriers
  k_zero<<<1, 256, 0, stream>>>((float*)bars, 128);
  // 2. embedding gathers
  k_gather<<<5120, 256, 0, stream>>>(src, trg, embed, emb_src_bf, emb_trg_bf);
  // 3. batched input projections
  {
    dim3 g1(32,16);
    k_gemm_aw<<<g1,256,0,stream>>>(emb_src_bf,256, eWihF,256, enc_in_f,2048, ebihF,ebhhF, 4096,256);
    k_gemm_aw<<<g1,256,0,stream>>>(emb_src_bf,256, eWihB,256, enc_in_b,2048, ebihB,ebhhB, 4096,256);
    dim3 g2(8,16);
    k_gemm_aw<<<g2,256,0,stream>>>(emb_trg_bf,256, dWih0,768, demb,2048, dbih0,dbhh0, 1024,256);
  }
  // 4. persistent encoder (both dirs)
  k_enc_persist<<<256, 256, 0, stream>>>(enc_in_f, enc_in_b, eWhhF, eWhhB,
                                         f_outs, b_outs, c_f, c_b, bars);
  // 5. sum directions
  k_sum_enc<<<8192, 256, 0, stream>>>(f_outs, b_outs, enc_sum, enc_sum_bf);
  // 6. attention enc projection (+attn_b)
  {
    dim3 g3(32,4);
    k_gemm_aw<<<g3,256,0,stream>>>(enc_sum_bf,512, attnW+512,1024, enc_proj,512, attnB,nullptr, 4096,512);
  }
  // 7. transpose qproj weights
  k_transpose512<<<64, 256, 0, stream>>>(attnW, WT);
  // 8. persistent decoder
  k_dec_persist<<<128, 256, 0, stream>>>(demb, dWih0+256, dWhh0, dWih1, dWhh1,
                                         dbih1, dbhh1, WT, attnV, enc_proj, enc_sum,
                                         f_outs + (size_t)127*16384, b_outs + (size_t)127*16384,
                                         c_f, c_b, h0buf, h1buf, ctxb, h1ctx, bars);
  // 9. outputs[0] = 0
  k_zero<<<512, 256, 0, stream>>>(out, 1024000);
  // 10. batched output projection
  {
    dim3 g4(8,250);
    k_gemm_aw<<<g4,256,0,stream>>>(h1ctx,1024, outW,1024, out + 1024000, 32000, outB,nullptr, 992,1024);
  }
  // 11. log_softmax
  k_logsm<<<992, 256, 0, stream>>>(out + 1024000);
}

// Round 3
// 6407.664 us; speedup vs baseline: 1.7529x; 1.7529x over previous
//
#include <hip/hip_runtime.h>
#include <stdint.h>

// V=32000, E=256, H=512, S=128, B=32, T=32

using short8 = __attribute__((ext_vector_type(8))) short;
using f32x4  = __attribute__((ext_vector_type(4))) float;

__device__ __forceinline__ short f2bf(float x){
  unsigned u = __float_as_uint(x);
  unsigned r = (u + 0x7fffu + ((u >> 16) & 1u)) >> 16;
  return (short)(unsigned short)r;
}
__device__ __forceinline__ float sigmf(float x){ return 1.0f/(1.0f + __expf(-x)); }
__device__ __forceinline__ float fast_tanh(float x){
  const float e = __expf(2.0f*x);
  return 1.0f - 2.0f/(e + 1.0f);
}

// ---------------------------------------------------------------------------
// coherent (LLC-meeting) loads/stores: sc0 sc1 bypass non-coherent L1/L2.
__device__ __forceinline__ float4 load_coh1(const float* p){
  float4 v;
  asm volatile("global_load_dwordx4 %0, %1, off sc0 sc1\n\t"
               "s_waitcnt vmcnt(0)"
               : "=&v"(v) : "v"(p) : "memory");
  return v;
}
__device__ __forceinline__ void load_coh16(const float* p, float4* d){
  asm volatile(
    "global_load_dwordx4 %0, %16, off sc0 sc1\n\t"
    "global_load_dwordx4 %1, %16, off offset:16 sc0 sc1\n\t"
    "global_load_dwordx4 %2, %16, off offset:32 sc0 sc1\n\t"
    "global_load_dwordx4 %3, %16, off offset:48 sc0 sc1\n\t"
    "global_load_dwordx4 %4, %16, off offset:64 sc0 sc1\n\t"
    "global_load_dwordx4 %5, %16, off offset:80 sc0 sc1\n\t"
    "global_load_dwordx4 %6, %16, off offset:96 sc0 sc1\n\t"
    "global_load_dwordx4 %7, %16, off offset:112 sc0 sc1\n\t"
    "global_load_dwordx4 %8, %16, off offset:128 sc0 sc1\n\t"
    "global_load_dwordx4 %9, %16, off offset:144 sc0 sc1\n\t"
    "global_load_dwordx4 %10, %16, off offset:160 sc0 sc1\n\t"
    "global_load_dwordx4 %11, %16, off offset:176 sc0 sc1\n\t"
    "global_load_dwordx4 %12, %16, off offset:192 sc0 sc1\n\t"
    "global_load_dwordx4 %13, %16, off offset:208 sc0 sc1\n\t"
    "global_load_dwordx4 %14, %16, off offset:224 sc0 sc1\n\t"
    "global_load_dwordx4 %15, %16, off offset:240 sc0 sc1\n\t"
    "s_waitcnt vmcnt(0)"
    : "=&v"(d[0]),"=&v"(d[1]),"=&v"(d[2]),"=&v"(d[3]),
      "=&v"(d[4]),"=&v"(d[5]),"=&v"(d[6]),"=&v"(d[7]),
      "=&v"(d[8]),"=&v"(d[9]),"=&v"(d[10]),"=&v"(d[11]),
      "=&v"(d[12]),"=&v"(d[13]),"=&v"(d[14]),"=&v"(d[15])
    : "v"(p)
    : "memory");
}
__device__ __forceinline__ void store_coh(float* p, float v){
  asm volatile("global_store_dword %0, %1, off sc0 sc1" :: "v"(p), "v"(v) : "memory");
}

// relaxed-only grid barrier: NO acquire/release (no cache invalidation).
// Correctness: each wave drains its own coherent stores (vmcnt 0), block
// barrier ensures all waves drained, then one relaxed RMW per block at LLC.
__device__ __forceinline__ void grid_bar(unsigned* cnt, unsigned* gen, unsigned n){
  asm volatile("s_waitcnt vmcnt(0)" ::: "memory");
  __syncthreads();
  if (threadIdx.x == 0){
    unsigned a = __hip_atomic_fetch_add(cnt, 1u, __ATOMIC_RELAXED, __HIP_MEMORY_SCOPE_AGENT);
    unsigned need = a / n + 1u;
    if (a % n == n - 1u){
      __hip_atomic_fetch_add(gen, 1u, __ATOMIC_RELAXED, __HIP_MEMORY_SCOPE_AGENT);
    } else {
      while (__hip_atomic_load(gen, __ATOMIC_RELAXED, __HIP_MEMORY_SCOPE_AGENT) < need){
        __builtin_amdgcn_s_sleep(2);
      }
    }
  }
  __syncthreads();
}

// ---------------------------------------------------------------------------
__global__ void k_zero(float* __restrict__ p, int n){
  int i = blockIdx.x*256 + threadIdx.x;
  const int stride = gridDim.x*256;
  for (; i < n; i += stride) p[i] = 0.f;
}

// ---------------------------------------------------------------------------
__global__ __launch_bounds__(256) void k_gather(
    const int* __restrict__ src, const int* __restrict__ trg,
    const float* __restrict__ embed,
    short* __restrict__ emb_src_bf, short* __restrict__ emb_trg_bf)
{
  const int row = blockIdx.x, tid = threadIdx.x;
  if (row < 4096){
    const int tok = src[row];
    emb_src_bf[(size_t)row*256 + tid] = f2bf(embed[(size_t)tok*256 + tid]);
  } else {
    const int r = row - 4096;
    short v = 0;
    if (r < 992){ const int tok = trg[r]; v = f2bf(embed[(size_t)tok*256 + tid]); }
    emb_trg_bf[(size_t)r*256 + tid] = v;
  }
}

// ---------------------------------------------------------------------------
// MFMA GEMM: C = A_bf16 @ W_f32^T + biases. tmode: C_T[t][col][b] (row=t*32+b)
__global__ __launch_bounds__(256) void k_gemm_aw(
    const short* __restrict__ A, int lda,
    const float* __restrict__ W, int ldw,
    float* __restrict__ C, int ldc,
    const float* __restrict__ bias0, const float* __restrict__ bias1,
    int Mvalid, int K, int tmode)
{
  __shared__ __align__(16) short As[128*32];
  __shared__ __align__(16) short Bs[128*32];
  const int tid = threadIdx.x;
  const int bm = blockIdx.x, bn = blockIdx.y;
  const int w  = tid >> 6,  l  = tid & 63;
  const int wm = w >> 1,    wn = w & 1;
  const int lr = l & 15,    lk = l >> 4;

  const int r0 = tid >> 2;
  const int s0 = (tid & 3) << 3;
  const int r1 = r0 + 64;

  const short* a0 = A + (size_t)(bm*128 + r0)*lda + s0;
  const short* a1 = A + (size_t)(bm*128 + r1)*lda + s0;
  const float* w0 = W + (size_t)(bn*128 + r0)*ldw + s0;
  const float* w1 = W + (size_t)(bn*128 + r1)*ldw + s0;

  const f32x4 zero4 = {0.f,0.f,0.f,0.f};
  f32x4 acc[4][4];
  #pragma unroll
  for (int mi=0;mi<4;mi++){
    #pragma unroll
    for (int ni=0;ni<4;ni++) acc[mi][ni] = zero4;
  }

  for (int k0 = 0; k0 < K; k0 += 32){
    short8 va0 = *(const short8*)(a0 + k0);
    short8 va1 = *(const short8*)(a1 + k0);
    float4 f00 = *(const float4*)(w0 + k0);
    float4 f01 = *(const float4*)(w0 + k0 + 4);
    float4 f10 = *(const float4*)(w1 + k0);
    float4 f11 = *(const float4*)(w1 + k0 + 4);
    short8 vb0, vb1;
    vb0[0]=f2bf(f00.x); vb0[1]=f2bf(f00.y); vb0[2]=f2bf(f00.z); vb0[3]=f2bf(f00.w);
    vb0[4]=f2bf(f01.x); vb0[5]=f2bf(f01.y); vb0[6]=f2bf(f01.z); vb0[7]=f2bf(f01.w);
    vb1[0]=f2bf(f10.x); vb1[1]=f2bf(f10.y); vb1[2]=f2bf(f10.z); vb1[3]=f2bf(f10.w);
    vb1[4]=f2bf(f11.x); vb1[5]=f2bf(f11.y); vb1[6]=f2bf(f11.z); vb1[7]=f2bf(f11.w);

    __syncthreads();
    *((short8*)As + tid)       = va0;
    *((short8*)As + tid + 256) = va1;
    *((short8*)Bs + tid)       = vb0;
    *((short8*)Bs + tid + 256) = vb1;
    __syncthreads();

    short8 af[4], bfr[4];
    #pragma unroll
    for (int mi=0;mi<4;mi++) af[mi]  = *(const short8*)&As[(wm*64 + mi*16 + lr)*32 + (lk<<3)];
    #pragma unroll
    for (int ni=0;ni<4;ni++) bfr[ni] = *(const short8*)&Bs[(wn*64 + ni*16 + lr)*32 + (lk<<3)];
    #pragma unroll
    for (int mi=0;mi<4;mi++){
      #pragma unroll
      for (int ni=0;ni<4;ni++)
        acc[mi][ni] = __builtin_amdgcn_mfma_f32_16x16x32_bf16(af[mi], bfr[ni], acc[mi][ni], 0,0,0);
    }
  }

  #pragma unroll
  for (int mi=0;mi<4;mi++){
    const int rb = bm*128 + wm*64 + mi*16 + (lk<<2);
    #pragma unroll
    for (int ni=0;ni<4;ni++){
      const int col = bn*128 + wn*64 + ni*16 + lr;
      float bv = 0.f;
      if (bias0) bv += bias0[col];
      if (bias1) bv += bias1[col];
      #pragma unroll
      for (int rr=0;rr<4;rr++){
        const int row = rb + rr;
        if (row < Mvalid){
          if (tmode) C[(size_t)(row>>5)*65536 + (size_t)col*32 + (row&31)] = acc[mi][ni][rr] + bv;
          else       C[(size_t)row*ldc + col] = acc[mi][ni][rr] + bv;
        }
      }
    }
  }
}

// ---------------------------------------------------------------------------
// WT[k][c] = attnW[c][k] for c,k < 512
__global__ __launch_bounds__(256) void k_transpose512(
    const float* __restrict__ A, float* __restrict__ AT)
{
  __shared__ float t[64][65];
  const int tid = threadIdx.x;
  const int kt = blockIdx.x & 7, ct = blockIdx.x >> 3;
  const int c0 = ct*64, k0 = kt*64;
  for (int i = tid; i < 1024; i += 256){
    const int r = i >> 4, q = i & 15;
    float4 v = *(const float4*)&A[(size_t)(c0+r)*1024 + k0 + (q<<2)];
    t[r][(q<<2)+0]=v.x; t[r][(q<<2)+1]=v.y; t[r][(q<<2)+2]=v.z; t[r][(q<<2)+3]=v.w;
  }
  __syncthreads();
  for (int i = tid; i < 1024; i += 256){
    const int r = i >> 4, q = i & 15;
    float4 v;
    v.x = t[(q<<2)+0][r]; v.y = t[(q<<2)+1][r];
    v.z = t[(q<<2)+2][r]; v.w = t[(q<<2)+3][r];
    *(float4*)&AT[(size_t)(k0+r)*512 + c0 + (q<<2)] = v;
  }
}

// ---------------------------------------------------------------------------
// persistent bidirectional encoder. 256 blocks: dir=bid&1, m=bid>>1.
// thread (b=tid&31, r=tid>>5): k-slice [64r,64r+64) of h, 16 gate-rows
// j = g*512 + 4m + o. Partials reduced via LDS; finish by 128 threads.
__global__ __launch_bounds__(256,1) void k_enc_persist(
    const float* __restrict__ pre_f, const float* __restrict__ pre_b,  // [128][2048][32]
    const float* __restrict__ Whh_f, const float* __restrict__ Whh_b,
    float* __restrict__ f_outs, float* __restrict__ b_outs,            // [128][32][512]
    float* __restrict__ c_f_out, float* __restrict__ c_b_out,
    unsigned* __restrict__ bars)
{
  __shared__ float zpart[16*256];     // [row][r*32+b]
  const int bid = blockIdx.x;
  const int dir = bid & 1;
  const int m   = bid >> 1;
  const float* pre = dir ? pre_b : pre_f;
  const float* Whh = dir ? Whh_b : Whh_f;
  float* outs  = dir ? b_outs : f_outs;
  float* c_out = dir ? c_b_out : c_f_out;
  unsigned* cnt = bars + (dir ? 16 : 0);
  unsigned* gen = cnt + 8;

  const int tid = threadIdx.x;
  const int b = tid & 31, r = tid >> 5;
  const float* wbase = Whh + (size_t)(m*4)*512 + r*64;

  const int b2 = tid & 31, o2 = (tid >> 5) & 3;
  const int k_out = m*4 + o2;
  float c_reg = 0.f;

  for (int t = 0; t < 128; ++t){
    float4 hv[16];
    if (t == 0){
      #pragma unroll
      for (int i=0;i<16;i++) hv[i] = make_float4(0.f,0.f,0.f,0.f);
    } else {
      load_coh16(outs + (size_t)(t-1)*16384 + b*512 + r*64, hv);
    }
    float acc[16];
    #pragma unroll
    for (int i=0;i<16;i++) acc[i]=0.f;
    #pragma unroll
    for (int c = 0; c < 16; ++c){
      const float4 h4 = hv[c];
      #pragma unroll
      for (int g = 0; g < 4; ++g){
        #pragma unroll
        for (int o = 0; o < 4; ++o){
          const float4 w = *(const float4*)&wbase[(size_t)(g*512+o)*512 + (c<<2)];
          float a = acc[g*4+o];
          a = fmaf(w.x, h4.x, a); a = fmaf(w.y, h4.y, a);
          a = fmaf(w.z, h4.z, a); a = fmaf(w.w, h4.w, a);
          acc[g*4+o] = a;
        }
      }
    }
    #pragma unroll
    for (int row = 0; row < 16; ++row) zpart[row*256 + (r<<5) + b] = acc[row];
    __syncthreads();
    if (tid < 128){
      const int tt = dir ? (127 - t) : t;
      const float* pt = pre + (size_t)tt*65536 + b2;
      float z[4];
      #pragma unroll
      for (int g = 0; g < 4; ++g){
        float s = pt[(size_t)(g*512 + k_out)*32];
        const float* zp = &zpart[(g*4+o2)*256 + b2];
        #pragma unroll
        for (int rr = 0; rr < 8; ++rr) s += zp[rr*32];
        z[g] = s;
      }
      const float cn = sigmf(z[1])*c_reg + sigmf(z[0])*fast_tanh(z[2]);
      c_reg = cn;
      store_coh(outs + (size_t)t*16384 + b2*512 + k_out, sigmf(z[3])*fast_tanh(cn));
    }
    grid_bar(cnt, gen, 128u);
  }
  if (tid < 128) c_out[b2*512 + k_out] = c_reg;
}

// ---------------------------------------------------------------------------
__global__ __launch_bounds__(256) void k_sum_enc(
    const float* __restrict__ f_outs, const float* __restrict__ b_outs,
    float* __restrict__ enc_sum, short* __restrict__ enc_sum_bf)
{
  const int i = blockIdx.x*256 + threadIdx.x;
  const int s = i >> 14, rem = i & 16383;
  const float v = f_outs[i] + b_outs[(size_t)(127 - s)*16384 + rem];
  enc_sum[i] = v;
  enc_sum_bf[i] = f2bf(v);
}

// ---------------------------------------------------------------------------
// persistent decoder: 128 blocks, 3 phases/step (A attn on blocks 0..31,
// B cell0, C cell1), fence-free barriers, coherent handoffs.
__global__ __launch_bounds__(256,1) void k_dec_persist(
    const float* __restrict__ demb,      // [32][2048][32] (incl. bih0+bhh0)
    const float* __restrict__ Wih0c,     // dWih0+256 (ld 768)
    const float* __restrict__ Whh0,
    const float* __restrict__ Wih1,
    const float* __restrict__ Whh1,
    const float* __restrict__ bih1, const float* __restrict__ bhh1,
    const float* __restrict__ WT,        // [512][512]
    const float* __restrict__ attnV,
    const float* __restrict__ enc_proj,  // [4096][512] incl. attn_b
    const float* __restrict__ enc_sum,   // [4096][512]
    const float* __restrict__ h0_init, const float* __restrict__ h1_init,
    const float* __restrict__ c0_init, const float* __restrict__ c1_init,
    float* __restrict__ h0buf, float* __restrict__ h1buf,   // [2][32][512]
    float* __restrict__ ctxb,                               // [32][512]
    short* __restrict__ h1ctx,                              // [31][32][1024] bf16
    unsigned* __restrict__ bars)
{
  __shared__ float zpart[16*256];
  __shared__ __align__(16) float q_h[512], q_s[512], v_s[512];
  __shared__ float part[256], aw[128], red[128];

  const int bid = blockIdx.x, tid = threadIdx.x;
  unsigned* dcnt = bars + 32;
  unsigned* dgen = bars + 40;

  const int b = tid & 31, r = tid >> 5;
  const int b2 = tid & 31, o2 = (tid >> 5) & 3;
  const int k_out = (bid<<2) + o2;

  float c0_reg = 0.f, c1_reg = 0.f;
  float bias1g[4];
  if (tid < 128){
    c0_reg = c0_init[b2*512 + k_out];
    c1_reg = c1_init[b2*512 + k_out];
    #pragma unroll
    for (int g=0;g<4;g++) bias1g[g] = bih1[g*512 + k_out] + bhh1[g*512 + k_out];
  }
  if (bid < 32 && tid < 128) ((float4*)v_s)[tid] = ((const float4*)attnV)[tid];

  for (int t = 0; t < 31; ++t){
    // ---------- Phase A: attention (blocks 0..31) ----------
    if (bid < 32){
      const int ab = bid;
      const float* h1src = (t==0 ? h1_init : h1buf + (size_t)(t&1)*16384) + ab*512;
      if (tid < 128) ((float4*)q_h)[tid] = load_coh1(h1src + (tid<<2));
      __syncthreads();
      {
        float a0=0.f, a1=0.f;
        const float2* wt2 = (const float2*)WT;
        #pragma unroll 4
        for (int k=0;k<512;++k){
          const float2 wv = wt2[k*256 + tid];
          const float hq = q_h[k];
          a0 = fmaf(hq, wv.x, a0); a1 = fmaf(hq, wv.y, a1);
        }
        q_s[2*tid] = a0; q_s[2*tid+1] = a1;
      }
      __syncthreads();
      {
        const int s = tid >> 1, half = tid & 1;
        const float* ep = enc_proj + ((size_t)(s*32 + ab))*512 + (half << 8);
        const float* qh = q_s + (half << 8);
        const float* vh = v_s + (half << 8);
        float p = 0.f;
        for (int kk = 0; kk < 256; kk += 4){
          const float4 e = *(const float4*)&ep[kk];
          p += fast_tanh(qh[kk+0] + e.x) * vh[kk+0];
          p += fast_tanh(qh[kk+1] + e.y) * vh[kk+1];
          p += fast_tanh(qh[kk+2] + e.z) * vh[kk+2];
          p += fast_tanh(qh[kk+3] + e.w) * vh[kk+3];
        }
        part[tid] = p;
      }
      __syncthreads();
      if (tid < 128){ const float sc = part[2*tid] + part[2*tid+1]; aw[tid] = sc; red[tid] = sc; }
      __syncthreads();
      for (int off = 64; off > 0; off >>= 1){
        if (tid < off) red[tid] = fmaxf(red[tid], red[tid+off]);
        __syncthreads();
      }
      const float mx = red[0];
      __syncthreads();
      if (tid < 128){ const float e = __expf(aw[tid] - mx); aw[tid] = e; red[tid] = e; }
      __syncthreads();
      for (int off = 64; off > 0; off >>= 1){
        if (tid < off) red[tid] += red[tid+off];
        __syncthreads();
      }
      const float inv = 1.0f / red[0];
      if (tid < 128) aw[tid] *= inv;
      __syncthreads();
      {
        const int cc = tid << 1;
        float x0 = 0.f, x1 = 0.f;
        for (int s2 = 0; s2 < 128; ++s2){
          const float a = aw[s2];
          const float* er = enc_sum + ((size_t)(s2*32 + ab))*512 + cc;
          x0 = fmaf(a, er[0], x0);
          x1 = fmaf(a, er[1], x1);
        }
        store_coh(ctxb + ab*512 + cc,     x0);
        store_coh(ctxb + ab*512 + cc + 1, x1);
        h1ctx[(size_t)t*32768 + ab*1024 + 512 + cc]     = f2bf(x0);
        h1ctx[(size_t)t*32768 + ab*1024 + 512 + cc + 1] = f2bf(x1);
      }
    }
    grid_bar(dcnt, dgen, 128u);

    // ---------- Phase B: cell0 (x = [ctx ; h0]) ----------
    {
      const float* xsrc = (r < 4)
        ? (ctxb + b*512 + r*128)
        : ((t == 0 ? h0_init : h0buf + (size_t)(t&1)*16384) + b*512 + (r-4)*128);
      const float* wb  = (r < 4) ? Wih0c : Whh0;
      const size_t wld = (r < 4) ? 768 : 512;
      const int koff   = (r & 3) * 128;
      const float* wrow[16];
      #pragma unroll
      for (int g=0; g<4; ++g)
        #pragma unroll
        for (int o=0; o<4; ++o)
          wrow[g*4+o] = wb + (size_t)(g*512 + (bid<<2) + o)*wld + koff;

      float acc[16];
      #pragma unroll
      for (int i=0;i<16;i++) acc[i]=0.f;
      #pragma unroll
      for (int half=0; half<2; ++half){
        float4 xv[16];
        load_coh16(xsrc + half*64, xv);
        #pragma unroll
        for (int c=0;c<16;++c){
          const float4 h4 = xv[c];
          #pragma unroll
          for (int row=0; row<16; ++row){
            const float4 w = *(const float4*)&wrow[row][half*64 + (c<<2)];
            float a = acc[row];
            a = fmaf(w.x,h4.x,a); a = fmaf(w.y,h4.y,a);
            a = fmaf(w.z,h4.z,a); a = fmaf(w.w,h4.w,a);
            acc[row]=a;
          }
        }
      }
      #pragma unroll
      for (int row=0;row<16;++row) zpart[row*256 + (r<<5) + b] = acc[row];
      __syncthreads();
      if (tid < 128){
        const float* pt = demb + (size_t)t*65536 + b2;
        float z[4];
        #pragma unroll
        for (int g=0;g<4;++g){
          float s = pt[(size_t)(g*512 + k_out)*32];
          const float* zp = &zpart[(g*4+o2)*256 + b2];
          #pragma unroll
          for (int rr=0;rr<8;++rr) s += zp[rr*32];
          z[g]=s;
        }
        const float cn = sigmf(z[1])*c0_reg + sigmf(z[0])*fast_tanh(z[2]);
        c0_reg = cn;
        store_coh(h0buf + (size_t)((t+1)&1)*16384 + b2*512 + k_out, sigmf(z[3])*fast_tanh(cn));
      }
    }
    grid_bar(dcnt, dgen, 128u);

    // ---------- Phase C: cell1 (x = [h0new ; h1prev]) ----------
    {
      const float* xsrc = (r < 4)
        ? (h0buf + (size_t)((t+1)&1)*16384 + b*512 + r*128)
        : ((t == 0 ? h1_init : h1buf + (size_t)(t&1)*16384) + b*512 + (r-4)*128);
      const float* wb  = (r < 4) ? Wih1 : Whh1;
      const int koff   = (r & 3) * 128;
      const float* wrow[16];
      #pragma unroll
      for (int g=0; g<4; ++g)
        #pragma unroll
        for (int o=0; o<4; ++o)
          wrow[g*4+o] = wb + (size_t)(g*512 + (bid<<2) + o)*512 + koff;

      float acc[16];
      #pragma unroll
      for (int i=0;i<16;i++) acc[i]=0.f;
      #pragma unroll
      for (int half=0; half<2; ++half){
        float4 xv[16];
        load_coh16(xsrc + half*64, xv);
        #pragma unroll
        for (int c=0;c<16;++c){
          const float4 h4 = xv[c];
          #pragma unroll
          for (int row=0; row<16; ++row){
            const float4 w = *(const float4*)&wrow[row][half*64 + (c<<2)];
            float a = acc[row];
            a = fmaf(w.x,h4.x,a); a = fmaf(w.y,h4.y,a);
            a = fmaf(w.z,h4.z,a); a = fmaf(w.w,h4.w,a);
            acc[row]=a;
          }
        }
      }
      #pragma unroll
      for (int row=0;row<16;++row) zpart[row*256 + (r<<5) + b] = acc[row];
      __syncthreads();
      if (tid < 128){
        float z[4];
        #pragma unroll
        for (int g=0;g<4;++g){
          float s = bias1g[g];
          const float* zp = &zpart[(g*4+o2)*256 + b2];
          #pragma unroll
          for (int rr=0;rr<8;++rr) s += zp[rr*32];
          z[g]=s;
        }
        const float cn = sigmf(z[1])*c1_reg + sigmf(z[0])*fast_tanh(z[2]);
        c1_reg = cn;
        const float hn = sigmf(z[3])*fast_tanh(cn);
        store_coh(h1buf + (size_t)((t+1)&1)*16384 + b2*512 + k_out, hn);
        h1ctx[(size_t)t*32768 + b2*1024 + k_out] = f2bf(hn);
      }
    }
    grid_bar(dcnt, dgen, 128u);
  }
}

// ---------------------------------------------------------------------------
__global__ __launch_bounds__(256) void k_logsm(float* __restrict__ out){
  float* row = out + (size_t)blockIdx.x * 32000;
  const int tid = threadIdx.x;
  __shared__ float red[256];
  float m = -3.4e38f;
  for (int i = tid; i < 32000; i += 256) m = fmaxf(m, row[i]);
  red[tid] = m; __syncthreads();
  for (int off = 128; off > 0; off >>= 1){
    if (tid < off) red[tid] = fmaxf(red[tid], red[tid+off]);
    __syncthreads();
  }
  m = red[0]; __syncthreads();
  float s = 0.f;
  for (int i = tid; i < 32000; i += 256) s += __expf(row[i] - m);
  red[tid] = s; __syncthreads();
  for (int off = 128; off > 0; off >>= 1){
    if (tid < off) red[tid] += red[tid+off];
    __syncthreads();
  }
  const float lse = m + __logf(red[0]);
  for (int i = tid; i < 32000; i += 256) row[i] -= lse;
}

// ---------------------------------------------------------------------------
extern "C" void kernel_launch(void* const* d_in, const int* in_sizes, int n_in,
                              void* d_out, int out_size, void* d_ws, size_t ws_size,
                              hipStream_t stream)
{
  (void)in_sizes; (void)n_in; (void)out_size; (void)ws_size;
  const int*   src   = (const int*)d_in[0];
  const int*   trg   = (const int*)d_in[1];
  const float* embed = (const float*)d_in[2];
  const float* eWihF = (const float*)d_in[3];
  const float* eWhhF = (const float*)d_in[4];
  const float* ebihF = (const float*)d_in[5];
  const float* ebhhF = (const float*)d_in[6];
  const float* eWihB = (const float*)d_in[7];
  const float* eWhhB = (const float*)d_in[8];
  const float* ebihB = (const float*)d_in[9];
  const float* ebhhB = (const float*)d_in[10];
  const float* attnW = (const float*)d_in[11];
  const float* attnB = (const float*)d_in[12];
  const float* attnV = (const float*)d_in[13];
  const float* dWih0 = (const float*)d_in[14];
  const float* dWhh0 = (const float*)d_in[15];
  const float* dbih0 = (const float*)d_in[16];
  const float* dbhh0 = (const float*)d_in[17];
  const float* dWih1 = (const float*)d_in[18];
  const float* dWhh1 = (const float*)d_in[19];
  const float* dbih1 = (const float*)d_in[20];
  const float* dbhh1 = (const float*)d_in[21];
  const float* outW  = (const float*)d_in[22];
  const float* outB  = (const float*)d_in[23];

  float* out = (float*)d_out;
  // d_out scratch (dead before final GEMM writes)
  float* enc_in_f = out;               // [128][2048][32] (transposed)
  float* enc_in_b = out + 8388608;     // [128][2048][32]
  float* enc_sum  = out + 16777216;    // [128][32][512]
  float* enc_proj = out + 18874368;    // [4096][512]
  float* f_outs   = out + 20971520;    // [128][32][512]
  float* b_outs   = out + 23068672;
  float* demb     = out + 25165824;    // [32][2048][32] (transposed)
  short* emb_src_bf = (short*)(out + 27262976);
  short* emb_trg_bf = (short*)(out + 27787264);
  short* enc_sum_bf = (short*)(out + 27918336);
  float* WT         = out + 28966912;  // [512][512]

  char* ws = (char*)d_ws;
  short* h1ctx = (short*)ws;           // [31][32][1024] bf16 (2 MB region)
  float* st    = (float*)(ws + 2097152);
  float* h0buf = st;                   // [2][32][512]
  float* h1buf = st + 32768;
  float* ctxb  = st + 65536;           // [32][512]
  float* c_f   = st + 81920;           // [32][512]
  float* c_b   = st + 98304;
  unsigned* bars = (unsigned*)(st + 114688);   // 48 uints used, 64B-spaced

  // 1. zero barrier flags
  k_zero<<<1, 256, 0, stream>>>((float*)bars, 256);
  // 2. embedding gathers
  k_gather<<<5120, 256, 0, stream>>>(src, trg, embed, emb_src_bf, emb_trg_bf);
  // 3. batched input projections (transposed outputs [t][j][b])
  {
    dim3 g1(32,16);
    k_gemm_aw<<<g1,256,0,stream>>>(emb_src_bf,256, eWihF,256, enc_in_f,2048, ebihF,ebhhF, 4096,256, 1);
    k_gemm_aw<<<g1,256,0,stream>>>(emb_src_bf,256, eWihB,256, enc_in_b,2048, ebihB,ebhhB, 4096,256, 1);
    dim3 g2(8,16);
    k_gemm_aw<<<g2,256,0,stream>>>(emb_trg_bf,256, dWih0,768, demb,2048, dbih0,dbhh0, 1024,256, 1);
  }
  // 4. persistent encoder (both dirs)
  k_enc_persist<<<256, 256, 0, stream>>>(enc_in_f, enc_in_b, eWhhF, eWhhB,
                                         f_outs, b_outs, c_f, c_b, bars);
  // 5. sum directions
  k_sum_enc<<<8192, 256, 0, stream>>>(f_outs, b_outs, enc_sum, enc_sum_bf);
  // 6. attention enc projection (+attn_b)
  {
    dim3 g3(32,4);
    k_gemm_aw<<<g3,256,0,stream>>>(enc_sum_bf,512, attnW+512,1024, enc_proj,512, attnB,nullptr, 4096,512, 0);
  }
  // 7. transpose qproj weights
  k_transpose512<<<64, 256, 0, stream>>>(attnW, WT);
  // 8. persistent decoder
  k_dec_persist<<<128, 256, 0, stream>>>(demb, dWih0+256, dWhh0, dWih1, dWhh1,
                                         dbih1, dbhh1, WT, attnV, enc_proj, enc_sum,
                                         f_outs + (size_t)127*16384, b_outs + (size_t)127*16384,
                                         c_f, c_b, h0buf, h1buf, ctxb, h1ctx, bars);
  // 9. outputs[0] = 0
  k_zero<<<512, 256, 0, stream>>>(out, 1024000);
  // 10. batched output projection
  {
    dim3 g4(8,250);
    k_gemm_aw<<<g4,256,0,stream>>>(h1ctx,1024, outW,1024, out + 1024000, 32000, outB,nullptr, 992,1024, 0);
  }
  // 11. log_softmax
  k_logsm<<<992, 256, 0, stream>>>(out + 1024000);
}

// Round 5
// 4113.380 us; speedup vs baseline: 2.7306x; 1.5578x over previous
//
#include <hip/hip_runtime.h>
#include <stdint.h>

// V=32000, E=256, H=512, S=128, B=32, T=32

using short8 = __attribute__((ext_vector_type(8))) short;
using f32x4  = __attribute__((ext_vector_type(4))) float;
typedef _Float16 half2v __attribute__((ext_vector_type(2)));

__device__ __forceinline__ short f2bf(float x){
  unsigned u = __float_as_uint(x);
  unsigned r = (u + 0x7fffu + ((u >> 16) & 1u)) >> 16;
  return (short)(unsigned short)r;
}
__device__ __forceinline__ float bf2f_lo(unsigned u){ return __uint_as_float(u << 16); }
__device__ __forceinline__ float bf2f_hi(unsigned u){ return __uint_as_float(u & 0xffff0000u); }
__device__ __forceinline__ float sigmf(float x){ return 1.0f/(1.0f + __expf(-x)); }
__device__ __forceinline__ float fast_tanh(float x){
  const float e = __expf(2.0f*x);
  return 1.0f - 2.0f/(e + 1.0f);
}
__device__ __forceinline__ unsigned pack_h2(float a, float b){
  unsigned short ha = __builtin_bit_cast(unsigned short, (_Float16)a);
  unsigned short hb = __builtin_bit_cast(unsigned short, (_Float16)b);
  return (unsigned)ha | ((unsigned)hb << 16);
}
__device__ __forceinline__ float dot2u(unsigned x, unsigned w, float c){
#if __has_builtin(__builtin_amdgcn_fdot2)
  return __builtin_amdgcn_fdot2(__builtin_bit_cast(half2v,x), __builtin_bit_cast(half2v,w), c, false);
#else
  half2v hx = __builtin_bit_cast(half2v,x), hw = __builtin_bit_cast(half2v,w);
  c = fmaf((float)hx[0], (float)hw[0], c);
  c = fmaf((float)hx[1], (float)hw[1], c);
  return c;
#endif
}

// ---------------------------------------------------------------------------
// coherent (LLC) accessors: sc0 sc1 bypass non-coherent L1/L2
__device__ __forceinline__ float4 load_coh_f4(const float* p){
  float4 v;
  asm volatile("global_load_dwordx4 %0, %1, off sc0 sc1\n\ts_waitcnt vmcnt(0)"
               : "=&v"(v) : "v"(p) : "memory");
  return v;
}
__device__ __forceinline__ uint4 load_coh_u4(const unsigned* p){
  uint4 v;
  asm volatile("global_load_dwordx4 %0, %1, off sc0 sc1\n\ts_waitcnt vmcnt(0)"
               : "=&v"(v) : "v"(p) : "memory");
  return v;
}
__device__ __forceinline__ void store_coh_f32(float* p, float v){
  asm volatile("global_store_dword %0, %1, off sc0 sc1" :: "v"(p), "v"(v) : "memory");
}
__device__ __forceinline__ void store_coh_u32(unsigned* p, unsigned v){
  asm volatile("global_store_dword %0, %1, off sc0 sc1" :: "v"(p), "v"(v) : "memory");
}

// one-sided flag sync: each block owns flags[id]; pollers wait all >= target.
__device__ __forceinline__ void wait_flags(const unsigned* flags, int quads, unsigned target){
  const unsigned* p = flags + (((threadIdx.x & 63) & (quads-1)) << 2);
  for(;;){
    uint4 v = load_coh_u4(p);
    bool ok = v.x>=target && v.y>=target && v.z>=target && v.w>=target;
    if (__all(ok)) break;
    asm volatile("s_sleep 1");
  }
}
__device__ __forceinline__ void set_flag(unsigned* slot, unsigned val){
  asm volatile("s_waitcnt vmcnt(0)" ::: "memory");
  __syncthreads();
  if (threadIdx.x == 0) store_coh_u32(slot, val);
}

// stage 8 rows x 512 f32 (row stride 512) -> LDS f16-pairs, row stride `ldl` uints
__device__ __forceinline__ void stage8(const float* src, unsigned* lds, int ldl, int kpoff){
  #pragma unroll
  for (int i = 0; i < 4; ++i){
    const int f = threadIdx.x + (i << 8);
    const int row = f >> 7, k4 = f & 127;
    float4 v = load_coh_f4(src + (size_t)row*512 + (k4<<2));
    lds[row*ldl + kpoff + (k4<<1)]     = pack_h2(v.x, v.y);
    lds[row*ldl + kpoff + (k4<<1) + 1] = pack_h2(v.z, v.w);
  }
}

// two 512-long f16 dot products (consecutive weight rows) vs LDS x
__device__ __forceinline__ float2 dot2rows(const unsigned* xrow, const unsigned* wA, const unsigned* wB){
  float a = 0.f, b = 0.f;
  #pragma unroll 8
  for (int it = 0; it < 32; ++it){
    uint4 x0 = *(const uint4*)(xrow + it*8);
    uint4 x1 = *(const uint4*)(xrow + it*8 + 4);
    uint4 a0 = *(const uint4*)(wA + it*8);
    uint4 a1 = *(const uint4*)(wA + it*8 + 4);
    uint4 b0 = *(const uint4*)(wB + it*8);
    uint4 b1 = *(const uint4*)(wB + it*8 + 4);
    a = dot2u(x0.x,a0.x,a); a = dot2u(x0.y,a0.y,a); a = dot2u(x0.z,a0.z,a); a = dot2u(x0.w,a0.w,a);
    a = dot2u(x1.x,a1.x,a); a = dot2u(x1.y,a1.y,a); a = dot2u(x1.z,a1.z,a); a = dot2u(x1.w,a1.w,a);
    b = dot2u(x0.x,b0.x,b); b = dot2u(x0.y,b0.y,b); b = dot2u(x0.z,b0.z,b); b = dot2u(x0.w,b0.w,b);
    b = dot2u(x1.x,b1.x,b); b = dot2u(x1.y,b1.y,b); b = dot2u(x1.w,b1.w,b); b = dot2u(x1.z,b1.z,b);
  }
  return make_float2(a, b);
}

// ---------------------------------------------------------------------------
__global__ void k_zero(float* __restrict__ p, int n){
  int i = blockIdx.x*256 + threadIdx.x;
  const int stride = gridDim.x*256;
  for (; i < n; i += stride) p[i] = 0.f;
}

__global__ __launch_bounds__(256) void k_cvt_f16(const float* __restrict__ s, unsigned short* __restrict__ d, int n){
  int i = blockIdx.x*256 + threadIdx.x;
  const int stride = gridDim.x*256;
  for (; i < n; i += stride) d[i] = __builtin_bit_cast(unsigned short, (_Float16)s[i]);
}
__global__ __launch_bounds__(256) void k_cvt_f16_str(const float* __restrict__ s, int lds_, unsigned short* __restrict__ d, int n){
  int i = blockIdx.x*256 + threadIdx.x;
  const int stride = gridDim.x*256;
  for (; i < n; i += stride){
    const int row = i >> 9, c = i & 511;
    d[i] = __builtin_bit_cast(unsigned short, (_Float16)s[(size_t)row*lds_ + c]);
  }
}

// ---------------------------------------------------------------------------
__global__ __launch_bounds__(256) void k_gather(
    const int* __restrict__ src, const int* __restrict__ trg,
    const float* __restrict__ embed,
    short* __restrict__ emb_src_bf, short* __restrict__ emb_trg_bf)
{
  const int row = blockIdx.x, tid = threadIdx.x;
  if (row < 4096){
    const int tok = src[row];
    emb_src_bf[(size_t)row*256 + tid] = f2bf(embed[(size_t)tok*256 + tid]);
  } else {
    const int r = row - 4096;
    short v = 0;
    if (r < 992){ const int tok = trg[r]; v = f2bf(embed[(size_t)tok*256 + tid]); }
    emb_trg_bf[(size_t)r*256 + tid] = v;
  }
}

// ---------------------------------------------------------------------------
// MFMA GEMM: A_bf16 @ W_f32^T + biases. tmode: C_T[t][col][b]; Cbf: bf16 output
__global__ __launch_bounds__(256) void k_gemm_aw(
    const short* __restrict__ A, int lda,
    const float* __restrict__ W, int ldw,
    float* __restrict__ C, int ldc,
    const float* __restrict__ bias0, const float* __restrict__ bias1,
    int Mvalid, int K, int tmode, short* __restrict__ Cbf)
{
  __shared__ __align__(16) short As[128*32];
  __shared__ __align__(16) short Bs[128*32];
  const int tid = threadIdx.x;
  const int bm = blockIdx.x, bn = blockIdx.y;
  const int w  = tid >> 6,  l  = tid & 63;
  const int wm = w >> 1,    wn = w & 1;
  const int lr = l & 15,    lk = l >> 4;

  const int r0 = tid >> 2;
  const int s0 = (tid & 3) << 3;
  const int r1 = r0 + 64;

  const short* a0 = A + (size_t)(bm*128 + r0)*lda + s0;
  const short* a1 = A + (size_t)(bm*128 + r1)*lda + s0;
  const float* w0 = W + (size_t)(bn*128 + r0)*ldw + s0;
  const float* w1 = W + (size_t)(bn*128 + r1)*ldw + s0;

  const f32x4 zero4 = {0.f,0.f,0.f,0.f};
  f32x4 acc[4][4];
  #pragma unroll
  for (int mi=0;mi<4;mi++){
    #pragma unroll
    for (int ni=0;ni<4;ni++) acc[mi][ni] = zero4;
  }

  for (int k0 = 0; k0 < K; k0 += 32){
    short8 va0 = *(const short8*)(a0 + k0);
    short8 va1 = *(const short8*)(a1 + k0);
    float4 f00 = *(const float4*)(w0 + k0);
    float4 f01 = *(const float4*)(w0 + k0 + 4);
    float4 f10 = *(const float4*)(w1 + k0);
    float4 f11 = *(const float4*)(w1 + k0 + 4);
    short8 vb0, vb1;
    vb0[0]=f2bf(f00.x); vb0[1]=f2bf(f00.y); vb0[2]=f2bf(f00.z); vb0[3]=f2bf(f00.w);
    vb0[4]=f2bf(f01.x); vb0[5]=f2bf(f01.y); vb0[6]=f2bf(f01.z); vb0[7]=f2bf(f01.w);
    vb1[0]=f2bf(f10.x); vb1[1]=f2bf(f10.y); vb1[2]=f2bf(f10.z); vb1[3]=f2bf(f10.w);
    vb1[4]=f2bf(f11.x); vb1[5]=f2bf(f11.y); vb1[6]=f2bf(f11.z); vb1[7]=f2bf(f11.w);

    __syncthreads();
    *((short8*)As + tid)       = va0;
    *((short8*)As + tid + 256) = va1;
    *((short8*)Bs + tid)       = vb0;
    *((short8*)Bs + tid + 256) = vb1;
    __syncthreads();

    short8 af[4], bfr[4];
    #pragma unroll
    for (int mi=0;mi<4;mi++) af[mi]  = *(const short8*)&As[(wm*64 + mi*16 + lr)*32 + (lk<<3)];
    #pragma unroll
    for (int ni=0;ni<4;ni++) bfr[ni] = *(const short8*)&Bs[(wn*64 + ni*16 + lr)*32 + (lk<<3)];
    #pragma unroll
    for (int mi=0;mi<4;mi++){
      #pragma unroll
      for (int ni=0;ni<4;ni++)
        acc[mi][ni] = __builtin_amdgcn_mfma_f32_16x16x32_bf16(af[mi], bfr[ni], acc[mi][ni], 0,0,0);
    }
  }

  #pragma unroll
  for (int mi=0;mi<4;mi++){
    const int rb = bm*128 + wm*64 + mi*16 + (lk<<2);
    #pragma unroll
    for (int ni=0;ni<4;ni++){
      const int col = bn*128 + wn*64 + ni*16 + lr;
      float bv = 0.f;
      if (bias0) bv += bias0[col];
      if (bias1) bv += bias1[col];
      #pragma unroll
      for (int rr=0;rr<4;rr++){
        const int row = rb + rr;
        if (row < Mvalid){
          const float vv = acc[mi][ni][rr] + bv;
          if (Cbf)        Cbf[(size_t)row*ldc + col] = f2bf(vv);
          else if (tmode) C[(size_t)(row>>5)*65536 + (size_t)col*32 + (row&31)] = vv;
          else            C[(size_t)row*ldc + col] = vv;
        }
      }
    }
  }
}

// ---------------------------------------------------------------------------
// WT[k][c] = attnW[c][k] for c,k < 512
__global__ __launch_bounds__(256) void k_transpose512(
    const float* __restrict__ A, float* __restrict__ AT)
{
  __shared__ float t[64][65];
  const int tid = threadIdx.x;
  const int kt = blockIdx.x & 7, ct = blockIdx.x >> 3;
  const int c0 = ct*64, k0 = kt*64;
  for (int i = tid; i < 1024; i += 256){
    const int r = i >> 4, q = i & 15;
    float4 v = *(const float4*)&A[(size_t)(c0+r)*1024 + k0 + (q<<2)];
    t[r][(q<<2)+0]=v.x; t[r][(q<<2)+1]=v.y; t[r][(q<<2)+2]=v.z; t[r][(q<<2)+3]=v.w;
  }
  __syncthreads();
  for (int i = tid; i < 1024; i += 256){
    const int r = i >> 4, q = i & 15;
    float4 v;
    v.x = t[(q<<2)+0][r]; v.y = t[(q<<2)+1][r];
    v.z = t[(q<<2)+2][r]; v.w = t[(q<<2)+3][r];
    *(float4*)&AT[(size_t)(k0+r)*512 + c0 + (q<<2)] = v;
  }
}

// ---------------------------------------------------------------------------
// persistent bidirectional encoder, 256 blocks.
// x=bid&7, m=bid>>3: dir=m&1, bg=(m>>1)&3, jb=x*4+(m>>3)
__global__ __launch_bounds__(256,1) void k_enc_persist(
    const float* __restrict__ pre_f, const float* __restrict__ pre_b,  // [128][2048][32] (+biases)
    const unsigned short* __restrict__ WhF, const unsigned short* __restrict__ WhB, // f16 [2048][512]
    float* __restrict__ f_outs, float* __restrict__ b_outs,            // [128][32][512]
    float* __restrict__ c_f_out, float* __restrict__ c_b_out,
    unsigned* __restrict__ flagF, unsigned* __restrict__ flagB)
{
  __shared__ __align__(16) unsigned x_lds[8*264];
  __shared__ float zbuf[64*8];
  const int bid = blockIdx.x, tid = threadIdx.x;
  const int x = bid & 7, m = bid >> 3;
  const int dir = m & 1, bg = (m >> 1) & 3, q = m >> 3;
  const int jb = x*4 + q;
  const float* pre = dir ? pre_b : pre_f;
  const unsigned* Wh = (const unsigned*)(dir ? WhB : WhF);
  float* outs = dir ? b_outs : f_outs;
  float* c_out = dir ? c_b_out : c_f_out;
  unsigned* flags = dir ? flagB : flagF;
  const int fid = jb + 32*bg;

  const int bb = tid & 7, rr = tid >> 3;
  const int g = rr >> 3, op = rr & 7;
  const unsigned* wA = Wh + (size_t)(g*512 + jb*16 + 2*op)*256;
  const unsigned* wB = wA + 256;

  const int fo = tid & 15, fb = tid >> 4;       // finish (tid<128)
  const int b_out = bg*8 + fb, k_out = jb*16 + fo;
  float c_reg = 0.f;

  for (int t = 0; t < 128; ++t){
    if (t) wait_flags(flags, 32, (unsigned)t);
    if (t == 0){
      for (int i = tid; i < 8*264; i += 256) x_lds[i] = 0;
    } else {
      stage8(outs + (size_t)(t-1)*16384 + (size_t)(bg*8)*512, x_lds, 264, 0);
    }
    __syncthreads();

    const float2 d = dot2rows(x_lds + bb*264, wA, wB);
    zbuf[(g*16 + 2*op)*8 + bb]   = d.x;
    zbuf[(g*16 + 2*op+1)*8 + bb] = d.y;
    __syncthreads();

    if (tid < 128){
      const int tt = dir ? (127 - t) : t;
      const float* pt = pre + (size_t)tt*65536;
      float z[4];
      #pragma unroll
      for (int gg = 0; gg < 4; ++gg)
        z[gg] = pt[(size_t)(gg*512 + k_out)*32 + b_out] + zbuf[(gg*16 + fo)*8 + fb];
      const float cn = sigmf(z[1])*c_reg + sigmf(z[0])*fast_tanh(z[2]);
      c_reg = cn;
      store_coh_f32(outs + (size_t)t*16384 + (size_t)b_out*512 + k_out, sigmf(z[3])*fast_tanh(cn));
    }
    set_flag(flags + fid, (unsigned)(t+1));
  }
  if (tid < 128) c_out[b_out*512 + k_out] = c_reg;
}

// ---------------------------------------------------------------------------
__global__ __launch_bounds__(256) void k_sum_enc(
    const float* __restrict__ f_outs, const float* __restrict__ b_outs,
    float* __restrict__ enc_sum, short* __restrict__ enc_sum_bf)
{
  const int i = blockIdx.x*256 + threadIdx.x;
  const int s = i >> 14, rem = i & 16383;
  const float v = f_outs[i] + b_outs[(size_t)(127 - s)*16384 + rem];
  enc_sum[i] = v;
  enc_sum_bf[i] = f2bf(v);
}

// ---------------------------------------------------------------------------
// persistent decoder, 256 blocks, 3 flag-synced phases/step.
// cells: jb = (bid&7)*8 + ((bid>>3)>>2) in 0..63, bg = (bid>>3)&3
__global__ __launch_bounds__(256,1) void k_dec_persist(
    const float* __restrict__ demb,               // [32][2048][32] (+bih0+bhh0)
    const unsigned short* __restrict__ Wih0h,     // f16 [2048][512]
    const unsigned short* __restrict__ Whh0h,
    const unsigned short* __restrict__ Wih1h,
    const unsigned short* __restrict__ Whh1h,
    const float* __restrict__ bih1, const float* __restrict__ bhh1,
    const float* __restrict__ WT,                 // f32 [512][512]
    const float* __restrict__ attnV,
    const short* __restrict__ enc_proj_bf,        // [4096][512] (+attn_b)
    const float* __restrict__ enc_sum,            // f32 [4096][512]
    const float* __restrict__ h0_init, const float* __restrict__ h1_init,
    const float* __restrict__ c0_init, const float* __restrict__ c1_init,
    float* __restrict__ h0buf, float* __restrict__ h1buf,  // [2][32][512]
    float* __restrict__ ctxb,                              // [32][512]
    short* __restrict__ h1ctx,                             // [31][32][1024] bf16
    unsigned* __restrict__ dflag)
{
  __shared__ __align__(16) unsigned x_lds[8*520];
  __shared__ float zpart[32*16];
  __shared__ __align__(16) float q_h[512], q_s[512], v_s[512];
  __shared__ float part[256], aw[128], red[128];

  const int bid = blockIdx.x, tid = threadIdx.x;
  const int jb = (bid & 7)*8 + ((bid >> 3) >> 2);
  const int bg = (bid >> 3) & 3;

  const int bb = tid & 7, idx = tid >> 3;
  const int kh = idx >> 4, rp = idx & 15;
  const int g = rp >> 2, op = rp & 3;
  const int rowA = g*512 + jb*8 + 2*op;

  const int fo = tid & 7, fb = tid >> 3;        // finish (tid<64)
  const int b_out = bg*8 + fb, k_out = jb*8 + fo;

  float c0_reg = 0.f, c1_reg = 0.f, bias1g[4];
  if (tid < 64){
    c0_reg = c0_init[b_out*512 + k_out];
    c1_reg = c1_init[b_out*512 + k_out];
    #pragma unroll
    for (int gg=0; gg<4; ++gg) bias1g[gg] = bih1[gg*512 + k_out] + bhh1[gg*512 + k_out];
  }
  if (bid < 32 && tid < 128) ((float4*)v_s)[tid] = ((const float4*)attnV)[tid];

  const unsigned* W0a = (const unsigned*)(kh ? Whh0h : Wih0h) + (size_t)rowA*256;
  const unsigned* W1a = (const unsigned*)(kh ? Whh1h : Wih1h) + (size_t)rowA*256;

  for (int t = 0; t < 31; ++t){
    // ---------------- Phase A: attention ----------------
    if (t) wait_flags(dflag, 64, (unsigned)(3*t));
    if (bid < 32){
      const int ab = bid;
      const float* h1src = (t==0 ? h1_init : h1buf + (size_t)(t&1)*16384) + ab*512;
      if (tid < 128) ((float4*)q_h)[tid] = load_coh_f4(h1src + (tid<<2));
      __syncthreads();
      {
        float a0=0.f, a1=0.f;
        const float2* wt2 = (const float2*)WT;
        #pragma unroll 4
        for (int k=0;k<512;++k){
          const float2 wv = wt2[k*256 + tid];
          const float hq = q_h[k];
          a0 = fmaf(hq, wv.x, a0); a1 = fmaf(hq, wv.y, a1);
        }
        q_s[2*tid] = a0; q_s[2*tid+1] = a1;
      }
      __syncthreads();
      {
        const int s = tid >> 1, half = tid & 1;
        const unsigned* ep = (const unsigned*)(enc_proj_bf + ((size_t)(s*32 + ab))*512 + (half << 8));
        const float* qh = q_s + (half << 8);
        const float* vh = v_s + (half << 8);
        float p = 0.f;
        for (int kk = 0; kk < 128; kk += 4){
          uint4 e = *(const uint4*)(ep + kk);
          const int k2 = kk << 1;
          p += fast_tanh(qh[k2+0] + bf2f_lo(e.x)) * vh[k2+0];
          p += fast_tanh(qh[k2+1] + bf2f_hi(e.x)) * vh[k2+1];
          p += fast_tanh(qh[k2+2] + bf2f_lo(e.y)) * vh[k2+2];
          p += fast_tanh(qh[k2+3] + bf2f_hi(e.y)) * vh[k2+3];
          p += fast_tanh(qh[k2+4] + bf2f_lo(e.z)) * vh[k2+4];
          p += fast_tanh(qh[k2+5] + bf2f_hi(e.z)) * vh[k2+5];
          p += fast_tanh(qh[k2+6] + bf2f_lo(e.w)) * vh[k2+6];
          p += fast_tanh(qh[k2+7] + bf2f_hi(e.w)) * vh[k2+7];
        }
        part[tid] = p;
      }
      __syncthreads();
      if (tid < 128){ const float sc = part[2*tid] + part[2*tid+1]; aw[tid] = sc; red[tid] = sc; }
      __syncthreads();
      for (int off = 64; off > 0; off >>= 1){
        if (tid < off) red[tid] = fmaxf(red[tid], red[tid+off]);
        __syncthreads();
      }
      const float mx = red[0];
      __syncthreads();
      if (tid < 128){ const float e = __expf(aw[tid] - mx); aw[tid] = e; red[tid] = e; }
      __syncthreads();
      for (int off = 64; off > 0; off >>= 1){
        if (tid < off) red[tid] += red[tid+off];
        __syncthreads();
      }
      const float inv = 1.0f / red[0];
      if (tid < 128) aw[tid] *= inv;
      __syncthreads();
      {
        const int cc = tid << 1;
        float x0 = 0.f, x1 = 0.f;
        for (int s2 = 0; s2 < 128; ++s2){
          const float2 er = *(const float2*)(enc_sum + ((size_t)(s2*32 + ab))*512 + cc);
          const float a = aw[s2];
          x0 = fmaf(a, er.x, x0);
          x1 = fmaf(a, er.y, x1);
        }
        store_coh_f32(ctxb + ab*512 + cc,     x0);
        store_coh_f32(ctxb + ab*512 + cc + 1, x1);
        h1ctx[(size_t)t*32768 + ab*1024 + 512 + cc]     = f2bf(x0);
        h1ctx[(size_t)t*32768 + ab*1024 + 512 + cc + 1] = f2bf(x1);
      }
    }
    set_flag(dflag + bid, (unsigned)(3*t+1));

    // ---------------- Phase B: cell0 (x = [ctx ; h0]) ----------------
    wait_flags(dflag, 64, (unsigned)(3*t+1));
    stage8(ctxb + (size_t)(bg*8)*512, x_lds, 520, 0);
    stage8((t==0 ? h0_init : h0buf + (size_t)(t&1)*16384) + (size_t)(bg*8)*512, x_lds, 520, 256);
    __syncthreads();
    {
      const float2 d = dot2rows(x_lds + bb*520 + kh*256, W0a, W0a + 256);
      zpart[(g*8 + 2*op)*16 + kh*8 + bb]   = d.x;
      zpart[(g*8 + 2*op+1)*16 + kh*8 + bb] = d.y;
    }
    __syncthreads();
    if (tid < 64){
      const float* pt = demb + (size_t)t*65536;
      float z[4];
      #pragma unroll
      for (int gg=0; gg<4; ++gg){
        const float* zp = &zpart[(gg*8 + fo)*16];
        z[gg] = pt[(size_t)(gg*512 + k_out)*32 + b_out] + zp[fb] + zp[8 + fb];
      }
      const float cn = sigmf(z[1])*c0_reg + sigmf(z[0])*fast_tanh(z[2]);
      c0_reg = cn;
      store_coh_f32(h0buf + (size_t)((t+1)&1)*16384 + (size_t)b_out*512 + k_out,
                    sigmf(z[3])*fast_tanh(cn));
    }
    set_flag(dflag + bid, (unsigned)(3*t+2));

    // ---------------- Phase C: cell1 (x = [h0new ; h1prev]) ----------------
    wait_flags(dflag, 64, (unsigned)(3*t+2));
    stage8(h0buf + (size_t)((t+1)&1)*16384 + (size_t)(bg*8)*512, x_lds, 520, 0);
    stage8((t==0 ? h1_init : h1buf + (size_t)(t&1)*16384) + (size_t)(bg*8)*512, x_lds, 520, 256);
    __syncthreads();
    {
      const float2 d = dot2rows(x_lds + bb*520 + kh*256, W1a, W1a + 256);
      zpart[(g*8 + 2*op)*16 + kh*8 + bb]   = d.x;
      zpart[(g*8 + 2*op+1)*16 + kh*8 + bb] = d.y;
    }
    __syncthreads();
    if (tid < 64){
      float z[4];
      #pragma unroll
      for (int gg=0; gg<4; ++gg){
        const float* zp = &zpart[(gg*8 + fo)*16];
        z[gg] = bias1g[gg] + zp[fb] + zp[8 + fb];
      }
      const float cn = sigmf(z[1])*c1_reg + sigmf(z[0])*fast_tanh(z[2]);
      c1_reg = cn;
      const float hn = sigmf(z[3])*fast_tanh(cn);
      store_coh_f32(h1buf + (size_t)((t+1)&1)*16384 + (size_t)b_out*512 + k_out, hn);
      h1ctx[(size_t)t*32768 + (size_t)b_out*1024 + k_out] = f2bf(hn);
    }
    set_flag(dflag + bid, (unsigned)(3*t+3));
  }
}

// ---------------------------------------------------------------------------
__global__ __launch_bounds__(256) void k_logsm(float* __restrict__ out){
  float* row = out + (size_t)blockIdx.x * 32000;
  const int tid = threadIdx.x;
  __shared__ float red[256];
  float m = -3.4e38f;
  for (int i = tid; i < 32000; i += 256) m = fmaxf(m, row[i]);
  red[tid] = m; __syncthreads();
  for (int off = 128; off > 0; off >>= 1){
    if (tid < off) red[tid] = fmaxf(red[tid], red[tid+off]);
    __syncthreads();
  }
  m = red[0]; __syncthreads();
  float s = 0.f;
  for (int i = tid; i < 32000; i += 256) s += __expf(row[i] - m);
  red[tid] = s; __syncthreads();
  for (int off = 128; off > 0; off >>= 1){
    if (tid < off) red[tid] += red[tid+off];
    __syncthreads();
  }
  const float lse = m + __logf(red[0]);
  for (int i = tid; i < 32000; i += 256) row[i] -= lse;
}

// ---------------------------------------------------------------------------
extern "C" void kernel_launch(void* const* d_in, const int* in_sizes, int n_in,
                              void* d_out, int out_size, void* d_ws, size_t ws_size,
                              hipStream_t stream)
{
  (void)in_sizes; (void)n_in; (void)out_size; (void)ws_size;
  const int*   src   = (const int*)d_in[0];
  const int*   trg   = (const int*)d_in[1];
  const float* embed = (const float*)d_in[2];
  const float* eWihF = (const float*)d_in[3];
  const float* eWhhF = (const float*)d_in[4];
  const float* ebihF = (const float*)d_in[5];
  const float* ebhhF = (const float*)d_in[6];
  const float* eWihB = (const float*)d_in[7];
  const float* eWhhB = (const float*)d_in[8];
  const float* ebihB = (const float*)d_in[9];
  const float* ebhhB = (const float*)d_in[10];
  const float* attnW = (const float*)d_in[11];
  const float* attnB = (const float*)d_in[12];
  const float* attnV = (const float*)d_in[13];
  const float* dWih0 = (const float*)d_in[14];
  const float* dWhh0 = (const float*)d_in[15];
  const float* dbih0 = (const float*)d_in[16];
  const float* dbhh0 = (const float*)d_in[17];
  const float* dWih1 = (const float*)d_in[18];
  const float* dWhh1 = (const float*)d_in[19];
  const float* dbih1 = (const float*)d_in[20];
  const float* dbhh1 = (const float*)d_in[21];
  const float* outW  = (const float*)d_in[22];
  const float* outB  = (const float*)d_in[23];

  float* out = (float*)d_out;
  // d_out scratch (all dead before final GEMM writes).
  // enc_sum (f32) aliases enc_in_f: written only AFTER encoder consumed enc_in_f.
  float* enc_in_f = out;                         // [128][2048][32]
  float* enc_sum  = out;                         // [128][32][512] (after encoder)
  float* enc_in_b = out + 8388608;
  short* enc_proj_bf = (short*)(out + 18874368); // [4096][512] bf16
  float* f_outs   = out + 20971520;              // [128][32][512]
  float* b_outs   = out + 23068672;
  float* demb     = out + 25165824;              // [32][2048][32]
  short* emb_src_bf = (short*)(out + 27262976);
  short* emb_trg_bf = (short*)(out + 27787264);
  short* enc_sum_bf = (short*)(out + 27918336);  // [4096][512] bf16
  float* WT         = out + 28966912;            // [512][512] f32
  unsigned short* whhF_h = (unsigned short*)(out + 29229056);  // each [2048][512] f16
  unsigned short* whhB_h = (unsigned short*)(out + 29753344);
  unsigned short* wih0_h = (unsigned short*)(out + 30277632);
  unsigned short* whh0_h = (unsigned short*)(out + 30801920);
  unsigned short* wih1_h = (unsigned short*)(out + 31326208);
  unsigned short* whh1_h = (unsigned short*)(out + 31850496);

  char* ws = (char*)d_ws;
  short* h1ctx = (short*)ws;                     // [31][32][1024] bf16
  float* st    = (float*)(ws + 2097152);
  float* h0buf = st;                             // [2][32][512]
  float* h1buf = st + 32768;
  float* ctxb  = st + 65536;                     // [32][512]
  float* c_f   = st + 81920;
  float* c_b   = st + 98304;
  unsigned* flagF = (unsigned*)(st + 114688);    // 128
  unsigned* flagB = flagF + 128;                 // 128
  unsigned* dflag = flagF + 256;                 // 256

  // 1. zero flags
  k_zero<<<1, 256, 0, stream>>>((float*)flagF, 512);
  // 2. embedding gathers
  k_gather<<<5120, 256, 0, stream>>>(src, trg, embed, emb_src_bf, emb_trg_bf);
  // 3. batched input projections (transposed [t][j][b])
  {
    dim3 g1(32,16);
    k_gemm_aw<<<g1,256,0,stream>>>(emb_src_bf,256, eWihF,256, enc_in_f,2048, ebihF,ebhhF, 4096,256, 1, nullptr);
    k_gemm_aw<<<g1,256,0,stream>>>(emb_src_bf,256, eWihB,256, enc_in_b,2048, ebihB,ebhhB, 4096,256, 1, nullptr);
    dim3 g2(8,16);
    k_gemm_aw<<<g2,256,0,stream>>>(emb_trg_bf,256, dWih0,768, demb,2048, dbih0,dbhh0, 1024,256, 1, nullptr);
  }
  // 4. f16 weight conversions
  k_cvt_f16<<<1024,256,0,stream>>>(eWhhF, whhF_h, 1048576);
  k_cvt_f16<<<1024,256,0,stream>>>(eWhhB, whhB_h, 1048576);
  k_cvt_f16_str<<<1024,256,0,stream>>>(dWih0+256, 768, wih0_h, 1048576);
  k_cvt_f16<<<1024,256,0,stream>>>(dWhh0, whh0_h, 1048576);
  k_cvt_f16<<<1024,256,0,stream>>>(dWih1, wih1_h, 1048576);
  k_cvt_f16<<<1024,256,0,stream>>>(dWhh1, whh1_h, 1048576);
  // 5. persistent encoder
  k_enc_persist<<<256, 256, 0, stream>>>(enc_in_f, enc_in_b, whhF_h, whhB_h,
                                         f_outs, b_outs, c_f, c_b, flagF, flagB);
  // 6. sum directions (f32 + bf16); enc_sum overwrites dead enc_in_f
  k_sum_enc<<<8192, 256, 0, stream>>>(f_outs, b_outs, enc_sum, enc_sum_bf);
  // 7. attention enc projection (+attn_b), bf16 out
  {
    dim3 g3(32,4);
    k_gemm_aw<<<g3,256,0,stream>>>(enc_sum_bf,512, attnW+512,1024, nullptr,512, attnB,nullptr, 4096,512, 0, enc_proj_bf);
  }
  // 8. transpose qproj weights
  k_transpose512<<<64, 256, 0, stream>>>(attnW, WT);
  // 9. persistent decoder
  k_dec_persist<<<256, 256, 0, stream>>>(demb, wih0_h, whh0_h, wih1_h, whh1_h,
                                         dbih1, dbhh1, WT, attnV, enc_proj_bf, enc_sum,
                                         f_outs + (size_t)127*16384, b_outs + (size_t)127*16384,
                                         c_f, c_b, h0buf, h1buf, ctxb, h1ctx, dflag);
  // 10. outputs[0] = 0
  k_zero<<<512, 256, 0, stream>>>(out, 1024000);
  // 11. batched output projection
  {
    dim3 g4(8,250);
    k_gemm_aw<<<g4,256,0,stream>>>(h1ctx,1024, outW,1024, out + 1024000, 32000, outB,nullptr, 992,1024, 0, nullptr);
  }
  // 12. log_softmax
  k_logsm<<<992, 256, 0, stream>>>(out + 1024000);
}

// Round 6
// 3249.140 us; speedup vs baseline: 3.4569x; 1.2660x over previous
//
#include <hip/hip_runtime.h>
#include <stdint.h>

// V=32000, E=256, H=512, S=128, B=32, T=32

using short8 = __attribute__((ext_vector_type(8))) short;
using f32x4  = __attribute__((ext_vector_type(4))) float;
typedef _Float16 half2v __attribute__((ext_vector_type(2)));

__device__ __forceinline__ short f2bf(float x){
  unsigned u = __float_as_uint(x);
  unsigned r = (u + 0x7fffu + ((u >> 16) & 1u)) >> 16;
  return (short)(unsigned short)r;
}
__device__ __forceinline__ float bf2f_lo(unsigned u){ return __uint_as_float(u << 16); }
__device__ __forceinline__ float bf2f_hi(unsigned u){ return __uint_as_float(u & 0xffff0000u); }
__device__ __forceinline__ float sigmf(float x){ return 1.0f/(1.0f + __expf(-x)); }
__device__ __forceinline__ float fast_tanh(float x){
  const float e = __expf(2.0f*x);
  return 1.0f - 2.0f/(e + 1.0f);
}
__device__ __forceinline__ unsigned pack_h2(float a, float b){
  unsigned short ha = __builtin_bit_cast(unsigned short, (_Float16)a);
  unsigned short hb = __builtin_bit_cast(unsigned short, (_Float16)b);
  return (unsigned)ha | ((unsigned)hb << 16);
}
__device__ __forceinline__ float dot2u(unsigned x, unsigned w, float c){
#if __has_builtin(__builtin_amdgcn_fdot2)
  return __builtin_amdgcn_fdot2(__builtin_bit_cast(half2v,x), __builtin_bit_cast(half2v,w), c, false);
#else
  half2v hx = __builtin_bit_cast(half2v,x), hw = __builtin_bit_cast(half2v,w);
  c = fmaf((float)hx[0], (float)hw[0], c);
  c = fmaf((float)hx[1], (float)hw[1], c);
  return c;
#endif
}

// ---------------------------------------------------------------------------
// coherent (LLC) accessors: sc0 sc1 bypass non-coherent L1/L2
__device__ __forceinline__ float4 load_coh_f4(const float* p){
  float4 v;
  asm volatile("global_load_dwordx4 %0, %1, off sc0 sc1\n\ts_waitcnt vmcnt(0)"
               : "=&v"(v) : "v"(p) : "memory");
  return v;
}
__device__ __forceinline__ uint4 load_coh_u4(const unsigned* p){
  uint4 v;
  asm volatile("global_load_dwordx4 %0, %1, off sc0 sc1\n\ts_waitcnt vmcnt(0)"
               : "=&v"(v) : "v"(p) : "memory");
  return v;
}
__device__ __forceinline__ void store_coh_f32(float* p, float v){
  asm volatile("global_store_dword %0, %1, off sc0 sc1" :: "v"(p), "v"(v) : "memory");
}
__device__ __forceinline__ void store_coh_u32(unsigned* p, unsigned v){
  asm volatile("global_store_dword %0, %1, off sc0 sc1" :: "v"(p), "v"(v) : "memory");
}

// one-sided flag sync: wave 0 polls; other waves wait at the barrier.
__device__ __forceinline__ void wait_flags(const unsigned* flags, int quads, unsigned target){
  if (threadIdx.x < 64){
    const unsigned* p = flags + ((threadIdx.x & (quads-1)) << 2);
    for(;;){
      uint4 v = load_coh_u4(p);
      if (__all(v.x>=target && v.y>=target && v.z>=target && v.w>=target)) break;
    }
  }
  __syncthreads();
}
__device__ __forceinline__ void set_flag(unsigned* slot, unsigned val){
  asm volatile("s_waitcnt vmcnt(0)" ::: "memory");
  __syncthreads();
  if (threadIdx.x == 0) store_coh_u32(slot, val);
}

// stage 8 rows x 512 f32 (row stride 512) -> LDS f16-pairs, row stride ldl uints
__device__ __forceinline__ void stage8(const float* src, unsigned* lds, int ldl, int kpoff){
  #pragma unroll
  for (int i = 0; i < 4; ++i){
    const int f = threadIdx.x + (i << 8);
    const int row = f >> 7, k4 = f & 127;
    float4 v = load_coh_f4(src + (size_t)row*512 + (k4<<2));
    lds[row*ldl + kpoff + (k4<<1)]     = pack_h2(v.x, v.y);
    lds[row*ldl + kpoff + (k4<<1) + 1] = pack_h2(v.z, v.w);
  }
}

// full 512-element f16 dot: x (LDS, 256 uints) . w (global f16 row, 256 uints)
__device__ __forceinline__ float dot512(const unsigned* xrow, const unsigned* w){
  float a = 0.f;
  #pragma unroll 4
  for (int it = 0; it < 16; ++it){
    uint4 x0 = *(const uint4*)(xrow + it*16);
    uint4 x1 = *(const uint4*)(xrow + it*16 + 4);
    uint4 x2 = *(const uint4*)(xrow + it*16 + 8);
    uint4 x3 = *(const uint4*)(xrow + it*16 + 12);
    uint4 w0 = *(const uint4*)(w + it*16);
    uint4 w1 = *(const uint4*)(w + it*16 + 4);
    uint4 w2 = *(const uint4*)(w + it*16 + 8);
    uint4 w3 = *(const uint4*)(w + it*16 + 12);
    a = dot2u(x0.x,w0.x,a); a = dot2u(x0.y,w0.y,a); a = dot2u(x0.z,w0.z,a); a = dot2u(x0.w,w0.w,a);
    a = dot2u(x1.x,w1.x,a); a = dot2u(x1.y,w1.y,a); a = dot2u(x1.z,w1.z,a); a = dot2u(x1.w,w1.w,a);
    a = dot2u(x2.x,w2.x,a); a = dot2u(x2.y,w2.y,a); a = dot2u(x2.z,w2.z,a); a = dot2u(x2.w,w2.w,a);
    a = dot2u(x3.x,w3.x,a); a = dot2u(x3.y,w3.y,a); a = dot2u(x3.z,w3.z,a); a = dot2u(x3.w,w3.w,a);
  }
  return a;
}

// two consecutive weight rows vs LDS x (encoder)
__device__ __forceinline__ float2 dot2rows(const unsigned* xrow, const unsigned* wA, const unsigned* wB){
  float a = 0.f, b = 0.f;
  #pragma unroll 8
  for (int it = 0; it < 32; ++it){
    uint4 x0 = *(const uint4*)(xrow + it*8);
    uint4 x1 = *(const uint4*)(xrow + it*8 + 4);
    uint4 a0 = *(const uint4*)(wA + it*8);
    uint4 a1 = *(const uint4*)(wA + it*8 + 4);
    uint4 b0 = *(const uint4*)(wB + it*8);
    uint4 b1 = *(const uint4*)(wB + it*8 + 4);
    a = dot2u(x0.x,a0.x,a); a = dot2u(x0.y,a0.y,a); a = dot2u(x0.z,a0.z,a); a = dot2u(x0.w,a0.w,a);
    a = dot2u(x1.x,a1.x,a); a = dot2u(x1.y,a1.y,a); a = dot2u(x1.z,a1.z,a); a = dot2u(x1.w,a1.w,a);
    b = dot2u(x0.x,b0.x,b); b = dot2u(x0.y,b0.y,b); b = dot2u(x0.z,b0.z,b); b = dot2u(x0.w,b0.w,b);
    b = dot2u(x1.x,b1.x,b); b = dot2u(x1.y,b1.y,b); b = dot2u(x1.z,b1.z,b); b = dot2u(x1.w,b1.w,b);
  }
  return make_float2(a, b);
}

// ---------------------------------------------------------------------------
__global__ void k_zero(float* __restrict__ p, int n){
  int i = blockIdx.x*256 + threadIdx.x;
  const int stride = gridDim.x*256;
  for (; i < n; i += stride) p[i] = 0.f;
}

__global__ __launch_bounds__(256) void k_cvt_f16(const float* __restrict__ s, unsigned short* __restrict__ d, int n){
  int i = blockIdx.x*256 + threadIdx.x;
  const int stride = gridDim.x*256;
  for (; i < n; i += stride) d[i] = __builtin_bit_cast(unsigned short, (_Float16)s[i]);
}
__global__ __launch_bounds__(256) void k_cvt_f16_str(const float* __restrict__ s, int lds_, unsigned short* __restrict__ d, int n){
  int i = blockIdx.x*256 + threadIdx.x;
  const int stride = gridDim.x*256;
  for (; i < n; i += stride){
    const int row = i >> 9, c = i & 511;
    d[i] = __builtin_bit_cast(unsigned short, (_Float16)s[(size_t)row*lds_ + c]);
  }
}

// ---------------------------------------------------------------------------
__global__ __launch_bounds__(256) void k_gather(
    const int* __restrict__ src, const int* __restrict__ trg,
    const float* __restrict__ embed,
    short* __restrict__ emb_src_bf, short* __restrict__ emb_trg_bf)
{
  const int row = blockIdx.x, tid = threadIdx.x;
  if (row < 4096){
    const int tok = src[row];
    emb_src_bf[(size_t)row*256 + tid] = f2bf(embed[(size_t)tok*256 + tid]);
  } else {
    const int r = row - 4096;
    short v = 0;
    if (r < 992){ const int tok = trg[r]; v = f2bf(embed[(size_t)tok*256 + tid]); }
    emb_trg_bf[(size_t)r*256 + tid] = v;
  }
}

// ---------------------------------------------------------------------------
// MFMA GEMM: A_bf16 @ W_f32^T + biases. tmode: C_T[t][col][b]; Cbf: bf16 output
__global__ __launch_bounds__(256) void k_gemm_aw(
    const short* __restrict__ A, int lda,
    const float* __restrict__ W, int ldw,
    float* __restrict__ C, int ldc,
    const float* __restrict__ bias0, const float* __restrict__ bias1,
    int Mvalid, int K, int tmode, short* __restrict__ Cbf)
{
  __shared__ __align__(16) short As[128*32];
  __shared__ __align__(16) short Bs[128*32];
  const int tid = threadIdx.x;
  const int bm = blockIdx.x, bn = blockIdx.y;
  const int w  = tid >> 6,  l  = tid & 63;
  const int wm = w >> 1,    wn = w & 1;
  const int lr = l & 15,    lk = l >> 4;

  const int r0 = tid >> 2;
  const int s0 = (tid & 3) << 3;
  const int r1 = r0 + 64;

  const short* a0 = A + (size_t)(bm*128 + r0)*lda + s0;
  const short* a1 = A + (size_t)(bm*128 + r1)*lda + s0;
  const float* w0 = W + (size_t)(bn*128 + r0)*ldw + s0;
  const float* w1 = W + (size_t)(bn*128 + r1)*ldw + s0;

  const f32x4 zero4 = {0.f,0.f,0.f,0.f};
  f32x4 acc[4][4];
  #pragma unroll
  for (int mi=0;mi<4;mi++){
    #pragma unroll
    for (int ni=0;ni<4;ni++) acc[mi][ni] = zero4;
  }

  for (int k0 = 0; k0 < K; k0 += 32){
    short8 va0 = *(const short8*)(a0 + k0);
    short8 va1 = *(const short8*)(a1 + k0);
    float4 f00 = *(const float4*)(w0 + k0);
    float4 f01 = *(const float4*)(w0 + k0 + 4);
    float4 f10 = *(const float4*)(w1 + k0);
    float4 f11 = *(const float4*)(w1 + k0 + 4);
    short8 vb0, vb1;
    vb0[0]=f2bf(f00.x); vb0[1]=f2bf(f00.y); vb0[2]=f2bf(f00.z); vb0[3]=f2bf(f00.w);
    vb0[4]=f2bf(f01.x); vb0[5]=f2bf(f01.y); vb0[6]=f2bf(f01.z); vb0[7]=f2bf(f01.w);
    vb1[0]=f2bf(f10.x); vb1[1]=f2bf(f10.y); vb1[2]=f2bf(f10.z); vb1[3]=f2bf(f10.w);
    vb1[4]=f2bf(f11.x); vb1[5]=f2bf(f11.y); vb1[6]=f2bf(f11.z); vb1[7]=f2bf(f11.w);

    __syncthreads();
    *((short8*)As + tid)       = va0;
    *((short8*)As + tid + 256) = va1;
    *((short8*)Bs + tid)       = vb0;
    *((short8*)Bs + tid + 256) = vb1;
    __syncthreads();

    short8 af[4], bfr[4];
    #pragma unroll
    for (int mi=0;mi<4;mi++) af[mi]  = *(const short8*)&As[(wm*64 + mi*16 + lr)*32 + (lk<<3)];
    #pragma unroll
    for (int ni=0;ni<4;ni++) bfr[ni] = *(const short8*)&Bs[(wn*64 + ni*16 + lr)*32 + (lk<<3)];
    #pragma unroll
    for (int mi=0;mi<4;mi++){
      #pragma unroll
      for (int ni=0;ni<4;ni++)
        acc[mi][ni] = __builtin_amdgcn_mfma_f32_16x16x32_bf16(af[mi], bfr[ni], acc[mi][ni], 0,0,0);
    }
  }

  #pragma unroll
  for (int mi=0;mi<4;mi++){
    const int rb = bm*128 + wm*64 + mi*16 + (lk<<2);
    #pragma unroll
    for (int ni=0;ni<4;ni++){
      const int col = bn*128 + wn*64 + ni*16 + lr;
      float bv = 0.f;
      if (bias0) bv += bias0[col];
      if (bias1) bv += bias1[col];
      #pragma unroll
      for (int rr=0;rr<4;rr++){
        const int row = rb + rr;
        if (row < Mvalid){
          const float vv = acc[mi][ni][rr] + bv;
          if (Cbf)        Cbf[(size_t)row*ldc + col] = f2bf(vv);
          else if (tmode) C[(size_t)(row>>5)*65536 + (size_t)col*32 + (row&31)] = vv;
          else            C[(size_t)row*ldc + col] = vv;
        }
      }
    }
  }
}

// ---------------------------------------------------------------------------
// persistent bidirectional encoder, 256 blocks.
// x=bid&7, m=bid>>3: dir=m&1, bg=(m>>1)&3, jb=x*4+(m>>3)
__global__ __launch_bounds__(256,1) void k_enc_persist(
    const float* __restrict__ pre_f, const float* __restrict__ pre_b,  // [128][2048][32] (+biases)
    const unsigned short* __restrict__ WhF, const unsigned short* __restrict__ WhB, // f16 [2048][512]
    float* __restrict__ f_outs, float* __restrict__ b_outs,            // [128][32][512]
    float* __restrict__ c_f_out, float* __restrict__ c_b_out,
    unsigned* __restrict__ flagF, unsigned* __restrict__ flagB)
{
  __shared__ __align__(16) unsigned x_lds[8*264];
  __shared__ float zbuf[64*8];
  const int bid = blockIdx.x, tid = threadIdx.x;
  const int x = bid & 7, m = bid >> 3;
  const int dir = m & 1, bg = (m >> 1) & 3, q = m >> 3;
  const int jb = x*4 + q;
  const float* pre = dir ? pre_b : pre_f;
  const unsigned* Wh = (const unsigned*)(dir ? WhB : WhF);
  float* outs = dir ? b_outs : f_outs;
  float* c_out = dir ? c_b_out : c_f_out;
  unsigned* flags = dir ? flagB : flagF;
  const int fid = jb + 32*bg;

  const int bb = tid & 7, rr = tid >> 3;
  const int g = rr >> 3, op = rr & 7;
  const unsigned* wA = Wh + (size_t)(g*512 + jb*16 + 2*op)*256;
  const unsigned* wB = wA + 256;

  const int fo = tid & 15, fb = tid >> 4;       // finish (tid<128)
  const int b_out = bg*8 + fb, k_out = jb*16 + fo;
  float c_reg = 0.f;

  for (int t = 0; t < 128; ++t){
    if (t) wait_flags(flags, 32, (unsigned)t);
    if (t == 0){
      for (int i = tid; i < 8*264; i += 256) x_lds[i] = 0;
    } else {
      stage8(outs + (size_t)(t-1)*16384 + (size_t)(bg*8)*512, x_lds, 264, 0);
    }
    __syncthreads();

    const float2 d = dot2rows(x_lds + bb*264, wA, wB);
    zbuf[(g*16 + 2*op)*8 + bb]   = d.x;
    zbuf[(g*16 + 2*op+1)*8 + bb] = d.y;
    __syncthreads();

    if (tid < 128){
      const int tt = dir ? (127 - t) : t;
      const float* pt = pre + (size_t)tt*65536;
      float z[4];
      #pragma unroll
      for (int gg = 0; gg < 4; ++gg)
        z[gg] = pt[(size_t)(gg*512 + k_out)*32 + b_out] + zbuf[(gg*16 + fo)*8 + fb];
      const float cn = sigmf(z[1])*c_reg + sigmf(z[0])*fast_tanh(z[2]);
      c_reg = cn;
      store_coh_f32(outs + (size_t)t*16384 + (size_t)b_out*512 + k_out, sigmf(z[3])*fast_tanh(cn));
    }
    set_flag(flags + fid, (unsigned)(t+1));
  }
  if (tid < 128) c_out[b_out*512 + k_out] = c_reg;
}

// ---------------------------------------------------------------------------
__global__ __launch_bounds__(256) void k_sum_enc(
    const float* __restrict__ f_outs, const float* __restrict__ b_outs,
    short* __restrict__ enc_sum_bf)
{
  const int i = blockIdx.x*256 + threadIdx.x;
  const int s = i >> 14, rem = i & 16383;
  enc_sum_bf[i] = f2bf(f_outs[i] + b_outs[(size_t)(127 - s)*16384 + rem]);
}

// ---------------------------------------------------------------------------
// persistent decoder, 256 blocks, 4 flag-synced phases/step.
// jb = (bid&7)*8 + ((bid>>3)>>2) in 0..63, bg = (bid>>3)&3; attn: blocks 0..31.
// P1: zh0=Whh0.h0[t-1], zh1=Whh1.h1[t-1] (regs), qs=Wq.h1[t-1] (global)
// P2: attn (scores/softmax/ctx) on 32 blocks
// P3: h0[t] = gates(demb + Wih0c.ctx + zh0)
// P4: h1[t] = gates(bias1 + Wih1.h0[t] + zh1)
__global__ __launch_bounds__(256,1) void k_dec_persist(
    const float* __restrict__ demb,               // [32][2048][32] (+bih0+bhh0)
    const unsigned short* __restrict__ Wih0h,     // f16 [2048][512]
    const unsigned short* __restrict__ Whh0h,
    const unsigned short* __restrict__ Wih1h,
    const unsigned short* __restrict__ Whh1h,
    const float* __restrict__ bih1, const float* __restrict__ bhh1,
    const unsigned short* __restrict__ wqh,       // f16 [512][512] (attnW cols 0..511)
    const float* __restrict__ attnV,
    const short* __restrict__ enc_proj_bf,        // [4096][512] (+attn_b)
    const short* __restrict__ enc_sum_bf,         // [4096][512]
    const float* __restrict__ h0_init, const float* __restrict__ h1_init,
    const float* __restrict__ c0_init, const float* __restrict__ c1_init,
    float* __restrict__ h0buf, float* __restrict__ h1buf,  // [2][32][512]
    float* __restrict__ ctxb,                              // [32][512]
    float* __restrict__ qsb,                               // [32][512]
    short* __restrict__ h1ctx,                             // [31][32][1024] bf16
    unsigned* __restrict__ dflag)
{
  __shared__ __align__(16) unsigned x0s[8*260];
  __shared__ __align__(16) unsigned x1s[8*260];
  __shared__ float zfin[32*9];
  __shared__ __align__(16) float q_s[512], v_s[512];
  __shared__ float part[256], aw[128], red[128];

  const int bid = blockIdx.x, tid = threadIdx.x;
  const int jb = (bid & 7)*8 + ((bid >> 3) >> 2);
  const int bg = (bid >> 3) & 3;

  const int b = tid & 7, r = tid >> 3;          // dot mapping
  const int g = r >> 3, o = r & 7;
  const int j_row = g*512 + jb*8 + o;

  const int fo = tid & 7, fb = tid >> 3;        // finish (tid<64)
  const int b_out = bg*8 + fb, k_out = jb*8 + fo;

  const unsigned* Wh0row = (const unsigned*)Whh0h + (size_t)j_row*256;
  const unsigned* Wh1row = (const unsigned*)Whh1h + (size_t)j_row*256;
  const unsigned* Wi0row = (const unsigned*)Wih0h + (size_t)j_row*256;
  const unsigned* Wi1row = (const unsigned*)Wih1h + (size_t)j_row*256;
  const unsigned* Wqrow  = (const unsigned*)wqh  + (size_t)(jb*8 + b)*256;

  float c0_reg = 0.f, c1_reg = 0.f, bias1g[4];
  if (tid < 64){
    c0_reg = c0_init[b_out*512 + k_out];
    c1_reg = c1_init[b_out*512 + k_out];
    #pragma unroll
    for (int gg=0; gg<4; ++gg) bias1g[gg] = bih1[gg*512 + k_out] + bhh1[gg*512 + k_out];
  }
  if (bid < 32 && tid < 128) ((float4*)v_s)[tid] = ((const float4*)attnV)[tid];

  for (int t = 0; t < 31; ++t){
    // ---------------- P1: h-dependent matvecs ----------------
    if (t) wait_flags(dflag, 64, (unsigned)(4*t));
    stage8((t==0 ? h0_init : h0buf + (size_t)(t&1)*16384) + (size_t)(bg*8)*512, x0s, 260, 0);
    stage8((t==0 ? h1_init : h1buf + (size_t)(t&1)*16384) + (size_t)(bg*8)*512, x1s, 260, 0);
    __syncthreads();
    const float zh0 = dot512(x0s + b*260, Wh0row);
    const float zh1 = dot512(x1s + b*260, Wh1row);
    if (tid < 64){
      const float q = dot512(x1s + (tid>>3)*260, Wqrow);
      store_coh_f32(qsb + (size_t)(bg*8 + (tid>>3))*512 + jb*8 + b, q);
    }

    // ---------------- P2: attention (blocks 0..31) ----------------
    if (bid < 32){
      set_flag(dflag + bid, (unsigned)(4*t+1));
      wait_flags(dflag, 64, (unsigned)(4*t+1));
      const int ab = bid;
      if (tid < 128) ((float4*)q_s)[tid] = load_coh_f4(qsb + (size_t)ab*512 + (tid<<2));
      __syncthreads();
      {
        const int s = tid >> 1, half = tid & 1;
        const unsigned* ep = (const unsigned*)(enc_proj_bf + ((size_t)(s*32 + ab))*512 + (half << 8));
        const float* qh = q_s + (half << 8);
        const float* vh = v_s + (half << 8);
        float p = 0.f;
        for (int kk = 0; kk < 128; kk += 4){
          uint4 e = *(const uint4*)(ep + kk);
          const int k2 = kk << 1;
          p += fast_tanh(qh[k2+0] + bf2f_lo(e.x)) * vh[k2+0];
          p += fast_tanh(qh[k2+1] + bf2f_hi(e.x)) * vh[k2+1];
          p += fast_tanh(qh[k2+2] + bf2f_lo(e.y)) * vh[k2+2];
          p += fast_tanh(qh[k2+3] + bf2f_hi(e.y)) * vh[k2+3];
          p += fast_tanh(qh[k2+4] + bf2f_lo(e.z)) * vh[k2+4];
          p += fast_tanh(qh[k2+5] + bf2f_hi(e.z)) * vh[k2+5];
          p += fast_tanh(qh[k2+6] + bf2f_lo(e.w)) * vh[k2+6];
          p += fast_tanh(qh[k2+7] + bf2f_hi(e.w)) * vh[k2+7];
        }
        part[tid] = p;
      }
      __syncthreads();
      if (tid < 128){ const float sc = part[2*tid] + part[2*tid+1]; aw[tid] = sc; red[tid] = sc; }
      __syncthreads();
      for (int off = 64; off > 0; off >>= 1){
        if (tid < off) red[tid] = fmaxf(red[tid], red[tid+off]);
        __syncthreads();
      }
      const float mx = red[0];
      __syncthreads();
      if (tid < 128){ const float e = __expf(aw[tid] - mx); aw[tid] = e; red[tid] = e; }
      __syncthreads();
      for (int off = 64; off > 0; off >>= 1){
        if (tid < off) red[tid] += red[tid+off];
        __syncthreads();
      }
      const float inv = 1.0f / red[0];
      if (tid < 128) aw[tid] *= inv;
      __syncthreads();
      {
        const int cc = tid << 1;
        float x0 = 0.f, x1 = 0.f;
        for (int s2 = 0; s2 < 128; ++s2){
          const unsigned u = *(const unsigned*)(enc_sum_bf + ((size_t)(s2*32 + ab))*512 + cc);
          const float a = aw[s2];
          x0 = fmaf(a, bf2f_lo(u), x0);
          x1 = fmaf(a, bf2f_hi(u), x1);
        }
        store_coh_f32(ctxb + ab*512 + cc,     x0);
        store_coh_f32(ctxb + ab*512 + cc + 1, x1);
        h1ctx[(size_t)t*32768 + ab*1024 + 512 + cc]     = f2bf(x0);
        h1ctx[(size_t)t*32768 + ab*1024 + 512 + cc + 1] = f2bf(x1);
      }
      set_flag(dflag + bid, (unsigned)(4*t+2));
    } else {
      set_flag(dflag + bid, (unsigned)(4*t+2));
    }

    // ---------------- P3: cell0 ----------------
    wait_flags(dflag, 64, (unsigned)(4*t+2));
    stage8(ctxb + (size_t)(bg*8)*512, x0s, 260, 0);
    __syncthreads();
    {
      const float z = demb[(size_t)t*65536 + (size_t)j_row*32 + bg*8 + b]
                    + dot512(x0s + b*260, Wi0row) + zh0;
      zfin[r*9 + b] = z;
    }
    __syncthreads();
    if (tid < 64){
      float z[4];
      #pragma unroll
      for (int gg=0; gg<4; ++gg) z[gg] = zfin[(gg*8 + fo)*9 + fb];
      const float cn = sigmf(z[1])*c0_reg + sigmf(z[0])*fast_tanh(z[2]);
      c0_reg = cn;
      store_coh_f32(h0buf + (size_t)((t+1)&1)*16384 + (size_t)b_out*512 + k_out,
                    sigmf(z[3])*fast_tanh(cn));
    }
    set_flag(dflag + bid, (unsigned)(4*t+3));

    // ---------------- P4: cell1 ----------------
    wait_flags(dflag, 64, (unsigned)(4*t+3));
    stage8(h0buf + (size_t)((t+1)&1)*16384 + (size_t)(bg*8)*512, x1s, 260, 0);
    __syncthreads();
    {
      const float z = dot512(x1s + b*260, Wi1row) + zh1;
      zfin[r*9 + b] = z;
    }
    __syncthreads();
    if (tid < 64){
      float z[4];
      #pragma unroll
      for (int gg=0; gg<4; ++gg) z[gg] = bias1g[gg] + zfin[(gg*8 + fo)*9 + fb];
      const float cn = sigmf(z[1])*c1_reg + sigmf(z[0])*fast_tanh(z[2]);
      c1_reg = cn;
      const float hn = sigmf(z[3])*fast_tanh(cn);
      store_coh_f32(h1buf + (size_t)((t+1)&1)*16384 + (size_t)b_out*512 + k_out, hn);
      h1ctx[(size_t)t*32768 + (size_t)b_out*1024 + k_out] = f2bf(hn);
    }
    set_flag(dflag + bid, (unsigned)(4*t+4));
  }
}

// ---------------------------------------------------------------------------
__global__ __launch_bounds__(256) void k_logsm(float* __restrict__ out){
  float* row = out + (size_t)blockIdx.x * 32000;
  const int tid = threadIdx.x;
  __shared__ float red[256];
  float m = -3.4e38f;
  for (int i = tid; i < 32000; i += 256) m = fmaxf(m, row[i]);
  red[tid] = m; __syncthreads();
  for (int off = 128; off > 0; off >>= 1){
    if (tid < off) red[tid] = fmaxf(red[tid], red[tid+off]);
    __syncthreads();
  }
  m = red[0]; __syncthreads();
  float s = 0.f;
  for (int i = tid; i < 32000; i += 256) s += __expf(row[i] - m);
  red[tid] = s; __syncthreads();
  for (int off = 128; off > 0; off >>= 1){
    if (tid < off) red[tid] += red[tid+off];
    __syncthreads();
  }
  const float lse = m + __logf(red[0]);
  for (int i = tid; i < 32000; i += 256) row[i] -= lse;
}

// ---------------------------------------------------------------------------
extern "C" void kernel_launch(void* const* d_in, const int* in_sizes, int n_in,
                              void* d_out, int out_size, void* d_ws, size_t ws_size,
                              hipStream_t stream)
{
  (void)in_sizes; (void)n_in; (void)out_size; (void)ws_size;
  const int*   src   = (const int*)d_in[0];
  const int*   trg   = (const int*)d_in[1];
  const float* embed = (const float*)d_in[2];
  const float* eWihF = (const float*)d_in[3];
  const float* eWhhF = (const float*)d_in[4];
  const float* ebihF = (const float*)d_in[5];
  const float* ebhhF = (const float*)d_in[6];
  const float* eWihB = (const float*)d_in[7];
  const float* eWhhB = (const float*)d_in[8];
  const float* ebihB = (const float*)d_in[9];
  const float* ebhhB = (const float*)d_in[10];
  const float* attnW = (const float*)d_in[11];
  const float* attnB = (const float*)d_in[12];
  const float* attnV = (const float*)d_in[13];
  const float* dWih0 = (const float*)d_in[14];
  const float* dWhh0 = (const float*)d_in[15];
  const float* dbih0 = (const float*)d_in[16];
  const float* dbhh0 = (const float*)d_in[17];
  const float* dWih1 = (const float*)d_in[18];
  const float* dWhh1 = (const float*)d_in[19];
  const float* dbih1 = (const float*)d_in[20];
  const float* dbhh1 = (const float*)d_in[21];
  const float* outW  = (const float*)d_in[22];
  const float* outB  = (const float*)d_in[23];

  float* out = (float*)d_out;
  // d_out scratch (all dead before final GEMM writes)
  float* enc_in_f = out;                         // [128][2048][32]
  float* enc_in_b = out + 8388608;
  short* enc_proj_bf = (short*)(out + 18874368); // [4096][512] bf16
  float* f_outs   = out + 20971520;              // [128][32][512]
  float* b_outs   = out + 23068672;
  float* demb     = out + 25165824;              // [32][2048][32]
  short* emb_src_bf = (short*)(out + 27262976);
  short* emb_trg_bf = (short*)(out + 27787264);
  short* enc_sum_bf = (short*)(out + 27918336);  // [4096][512] bf16
  unsigned short* wqh    = (unsigned short*)(out + 28966912);  // [512][512] f16
  unsigned short* whhF_h = (unsigned short*)(out + 29229056);  // each [2048][512] f16
  unsigned short* whhB_h = (unsigned short*)(out + 29753344);
  unsigned short* wih0_h = (unsigned short*)(out + 30277632);
  unsigned short* whh0_h = (unsigned short*)(out + 30801920);
  unsigned short* wih1_h = (unsigned short*)(out + 31326208);
  unsigned short* whh1_h = (unsigned short*)(out + 31850496);
  float* qsb            = out + 32374784;        // [32][512] f32

  char* ws = (char*)d_ws;
  short* h1ctx = (short*)ws;                     // [31][32][1024] bf16
  float* st    = (float*)(ws + 2097152);
  float* h0buf = st;                             // [2][32][512]
  float* h1buf = st + 32768;
  float* ctxb  = st + 65536;                     // [32][512]
  float* c_f   = st + 81920;
  float* c_b   = st + 98304;
  unsigned* flagF = (unsigned*)(st + 114688);    // 128
  unsigned* flagB = flagF + 128;                 // 128
  unsigned* dflag = flagF + 256;                 // 256

  // 1. zero flags
  k_zero<<<1, 256, 0, stream>>>((float*)flagF, 512);
  // 2. embedding gathers
  k_gather<<<5120, 256, 0, stream>>>(src, trg, embed, emb_src_bf, emb_trg_bf);
  // 3. batched input projections (transposed [t][j][b])
  {
    dim3 g1(32,16);
    k_gemm_aw<<<g1,256,0,stream>>>(emb_src_bf,256, eWihF,256, enc_in_f,2048, ebihF,ebhhF, 4096,256, 1, nullptr);
    k_gemm_aw<<<g1,256,0,stream>>>(emb_src_bf,256, eWihB,256, enc_in_b,2048, ebihB,ebhhB, 4096,256, 1, nullptr);
    dim3 g2(8,16);
    k_gemm_aw<<<g2,256,0,stream>>>(emb_trg_bf,256, dWih0,768, demb,2048, dbih0,dbhh0, 1024,256, 1, nullptr);
  }
  // 4. f16 weight conversions
  k_cvt_f16<<<1024,256,0,stream>>>(eWhhF, whhF_h, 1048576);
  k_cvt_f16<<<1024,256,0,stream>>>(eWhhB, whhB_h, 1048576);
  k_cvt_f16_str<<<1024,256,0,stream>>>(dWih0+256, 768, wih0_h, 1048576);
  k_cvt_f16<<<1024,256,0,stream>>>(dWhh0, whh0_h, 1048576);
  k_cvt_f16<<<1024,256,0,stream>>>(dWih1, wih1_h, 1048576);
  k_cvt_f16<<<1024,256,0,stream>>>(dWhh1, whh1_h, 1048576);
  k_cvt_f16_str<<<256,256,0,stream>>>(attnW, 1024, wqh, 262144);
  // 5. persistent encoder
  k_enc_persist<<<256, 256, 0, stream>>>(enc_in_f, enc_in_b, whhF_h, whhB_h,
                                         f_outs, b_outs, c_f, c_b, flagF, flagB);
  // 6. sum directions (bf16)
  k_sum_enc<<<8192, 256, 0, stream>>>(f_outs, b_outs, enc_sum_bf);
  // 7. attention enc projection (+attn_b), bf16 out
  {
    dim3 g3(32,4);
    k_gemm_aw<<<g3,256,0,stream>>>(enc_sum_bf,512, attnW+512,1024, nullptr,512, attnB,nullptr, 4096,512, 0, enc_proj_bf);
  }
  // 8. persistent decoder
  k_dec_persist<<<256, 256, 0, stream>>>(demb, wih0_h, whh0_h, wih1_h, whh1_h,
                                         dbih1, dbhh1, wqh, attnV, enc_proj_bf, enc_sum_bf,
                                         f_outs + (size_t)127*16384, b_outs + (size_t)127*16384,
                                         c_f, c_b, h0buf, h1buf, ctxb, qsb, h1ctx, dflag);
  // 9. outputs[0] = 0
  k_zero<<<512, 256, 0, stream>>>(out, 1024000);
  // 10. batched output projection
  {
    dim3 g4(8,250);
    k_gemm_aw<<<g4,256,0,stream>>>(h1ctx,1024, outW,1024, out + 1024000, 32000, outB,nullptr, 992,1024, 0, nullptr);
  }
  // 11. log_softmax
  k_logsm<<<992, 256, 0, stream>>>(out + 1024000);
}

// Round 7
// 2373.766 us; speedup vs baseline: 4.7317x; 1.3688x over previous
//
#include <hip/hip_runtime.h>
#include <stdint.h>

// V=32000, E=256, H=512, S=128, B=32, T=32

using short8 = __attribute__((ext_vector_type(8))) short;
using f32x4  = __attribute__((ext_vector_type(4))) float;
typedef _Float16 half2v __attribute__((ext_vector_type(2)));

__device__ __forceinline__ short f2bf(float x){
  unsigned u = __float_as_uint(x);
  unsigned r = (u + 0x7fffu + ((u >> 16) & 1u)) >> 16;
  return (short)(unsigned short)r;
}
__device__ __forceinline__ float bf2f_lo(unsigned u){ return __uint_as_float(u << 16); }
__device__ __forceinline__ float bf2f_hi(unsigned u){ return __uint_as_float(u & 0xffff0000u); }
__device__ __forceinline__ float sigmf(float x){ return 1.0f/(1.0f + __expf(-x)); }
__device__ __forceinline__ float fast_tanh(float x){
  const float e = __expf(2.0f*x);
  return 1.0f - 2.0f/(e + 1.0f);
}
__device__ __forceinline__ unsigned pack_h2(float a, float b){
  unsigned short ha = __builtin_bit_cast(unsigned short, (_Float16)a);
  unsigned short hb = __builtin_bit_cast(unsigned short, (_Float16)b);
  return (unsigned)ha | ((unsigned)hb << 16);
}
__device__ __forceinline__ float dot2u(unsigned x, unsigned w, float c){
#if __has_builtin(__builtin_amdgcn_fdot2)
  return __builtin_amdgcn_fdot2(__builtin_bit_cast(half2v,x), __builtin_bit_cast(half2v,w), c, false);
#else
  half2v hx = __builtin_bit_cast(half2v,x), hw = __builtin_bit_cast(half2v,w);
  c = fmaf((float)hx[0], (float)hw[0], c);
  c = fmaf((float)hx[1], (float)hw[1], c);
  return c;
#endif
}

// ---------------------------------------------------------------------------
// coherent (LLC) accessors: sc0 sc1 bypass non-coherent L1/L2
__device__ __forceinline__ float4 load_coh_f4(const float* p){
  float4 v;
  asm volatile("global_load_dwordx4 %0, %1, off sc0 sc1\n\ts_waitcnt vmcnt(0)"
               : "=&v"(v) : "v"(p) : "memory");
  return v;
}
__device__ __forceinline__ uint4 load_coh_u4(const unsigned* p){
  uint4 v;
  asm volatile("global_load_dwordx4 %0, %1, off sc0 sc1\n\ts_waitcnt vmcnt(0)"
               : "=&v"(v) : "v"(p) : "memory");
  return v;
}
// batched: 4 coherent 16B loads, ONE waitcnt (one LLC round-trip)
__device__ __forceinline__ void load_coh_f4x4(const float* p0, const float* p1,
                                              const float* p2, const float* p3, float4* d){
  asm volatile(
    "global_load_dwordx4 %0, %4, off sc0 sc1\n\t"
    "global_load_dwordx4 %1, %5, off sc0 sc1\n\t"
    "global_load_dwordx4 %2, %6, off sc0 sc1\n\t"
    "global_load_dwordx4 %3, %7, off sc0 sc1\n\t"
    "s_waitcnt vmcnt(0)"
    : "=&v"(d[0]),"=&v"(d[1]),"=&v"(d[2]),"=&v"(d[3])
    : "v"(p0),"v"(p1),"v"(p2),"v"(p3)
    : "memory");
}
__device__ __forceinline__ void store_coh_f32(float* p, float v){
  asm volatile("global_store_dword %0, %1, off sc0 sc1" :: "v"(p), "v"(v) : "memory");
}
__device__ __forceinline__ void store_coh_u32(unsigned* p, unsigned v){
  asm volatile("global_store_dword %0, %1, off sc0 sc1" :: "v"(p), "v"(v) : "memory");
}

// one-sided flag sync: wave 0 polls `quads` uint4s at base; others wait at barrier.
__device__ __forceinline__ void wait_flags(const unsigned* base, int quads, unsigned target){
  if (threadIdx.x < 64){
    const unsigned* p = base + ((threadIdx.x & (quads-1)) << 2);
    for(;;){
      uint4 v = load_coh_u4(p);
      if (__all(v.x>=target && v.y>=target && v.z>=target && v.w>=target)) break;
    }
  }
  __syncthreads();
}
__device__ __forceinline__ void set_flag(unsigned* slot, unsigned val){
  asm volatile("s_waitcnt vmcnt(0)" ::: "memory");
  __syncthreads();
  if (threadIdx.x == 0) store_coh_u32(slot, val);
}

// stage 8 rows x 512 f32 (row stride 512) -> LDS f16-pairs, row stride ldl uints.
// single batched waitcnt.
__device__ __forceinline__ void stage8b(const float* src, unsigned* lds, int ldl){
  const int tid = threadIdx.x;
  const int row0 = tid >> 7;          // 0 or 1
  const int k4 = tid & 127;
  const float* p0 = src + (size_t)(row0    )*512 + (k4<<2);
  const float* p1 = src + (size_t)(row0 + 2)*512 + (k4<<2);
  const float* p2 = src + (size_t)(row0 + 4)*512 + (k4<<2);
  const float* p3 = src + (size_t)(row0 + 6)*512 + (k4<<2);
  float4 v[4];
  load_coh_f4x4(p0, p1, p2, p3, v);
  #pragma unroll
  for (int i = 0; i < 4; ++i){
    const int row = row0 + 2*i;
    lds[row*ldl + (k4<<1)]     = pack_h2(v[i].x, v[i].y);
    lds[row*ldl + (k4<<1) + 1] = pack_h2(v[i].z, v[i].w);
  }
}

// full 512-element f16 dot: x (LDS, 256 uints) . w (global f16 row, 256 uints)
__device__ __forceinline__ float dot512(const unsigned* xrow, const unsigned* w){
  float a = 0.f;
  #pragma unroll 4
  for (int it = 0; it < 16; ++it){
    uint4 x0 = *(const uint4*)(xrow + it*16);
    uint4 x1 = *(const uint4*)(xrow + it*16 + 4);
    uint4 x2 = *(const uint4*)(xrow + it*16 + 8);
    uint4 x3 = *(const uint4*)(xrow + it*16 + 12);
    uint4 w0 = *(const uint4*)(w + it*16);
    uint4 w1 = *(const uint4*)(w + it*16 + 4);
    uint4 w2 = *(const uint4*)(w + it*16 + 8);
    uint4 w3 = *(const uint4*)(w + it*16 + 12);
    a = dot2u(x0.x,w0.x,a); a = dot2u(x0.y,w0.y,a); a = dot2u(x0.z,w0.z,a); a = dot2u(x0.w,w0.w,a);
    a = dot2u(x1.x,w1.x,a); a = dot2u(x1.y,w1.y,a); a = dot2u(x1.z,w1.z,a); a = dot2u(x1.w,w1.w,a);
    a = dot2u(x2.x,w2.x,a); a = dot2u(x2.y,w2.y,a); a = dot2u(x2.z,w2.z,a); a = dot2u(x2.w,w2.w,a);
    a = dot2u(x3.x,w3.x,a); a = dot2u(x3.y,w3.y,a); a = dot2u(x3.z,w3.z,a); a = dot2u(x3.w,w3.w,a);
  }
  return a;
}

// two consecutive weight rows vs LDS x (encoder)
__device__ __forceinline__ float2 dot2rows(const unsigned* xrow, const unsigned* wA, const unsigned* wB){
  float a = 0.f, b = 0.f;
  #pragma unroll 8
  for (int it = 0; it < 32; ++it){
    uint4 x0 = *(const uint4*)(xrow + it*8);
    uint4 x1 = *(const uint4*)(xrow + it*8 + 4);
    uint4 a0 = *(const uint4*)(wA + it*8);
    uint4 a1 = *(const uint4*)(wA + it*8 + 4);
    uint4 b0 = *(const uint4*)(wB + it*8);
    uint4 b1 = *(const uint4*)(wB + it*8 + 4);
    a = dot2u(x0.x,a0.x,a); a = dot2u(x0.y,a0.y,a); a = dot2u(x0.z,a0.z,a); a = dot2u(x0.w,a0.w,a);
    a = dot2u(x1.x,a1.x,a); a = dot2u(x1.y,a1.y,a); a = dot2u(x1.z,a1.z,a); a = dot2u(x1.w,a1.w,a);
    b = dot2u(x0.x,b0.x,b); b = dot2u(x0.y,b0.y,b); b = dot2u(x0.z,b0.z,b); b = dot2u(x0.w,b0.w,b);
    b = dot2u(x1.x,b1.x,b); b = dot2u(x1.y,b1.y,b); b = dot2u(x1.w,b1.w,b); b = dot2u(x1.z,b1.z,b);
  }
  return make_float2(a, b);
}

// ---------------------------------------------------------------------------
__global__ void k_zero(float* __restrict__ p, int n){
  int i = blockIdx.x*256 + threadIdx.x;
  const int stride = gridDim.x*256;
  for (; i < n; i += stride) p[i] = 0.f;
}

__global__ __launch_bounds__(256) void k_cvt_f16(const float* __restrict__ s, unsigned short* __restrict__ d, int n){
  int i = blockIdx.x*256 + threadIdx.x;
  const int stride = gridDim.x*256;
  for (; i < n; i += stride) d[i] = __builtin_bit_cast(unsigned short, (_Float16)s[i]);
}
__global__ __launch_bounds__(256) void k_cvt_f16_str(const float* __restrict__ s, int lds_, unsigned short* __restrict__ d, int n){
  int i = blockIdx.x*256 + threadIdx.x;
  const int stride = gridDim.x*256;
  for (; i < n; i += stride){
    const int row = i >> 9, c = i & 511;
    d[i] = __builtin_bit_cast(unsigned short, (_Float16)s[(size_t)row*lds_ + c]);
  }
}

// ---------------------------------------------------------------------------
__global__ __launch_bounds__(256) void k_gather(
    const int* __restrict__ src, const int* __restrict__ trg,
    const float* __restrict__ embed,
    short* __restrict__ emb_src_bf, short* __restrict__ emb_trg_bf)
{
  const int row = blockIdx.x, tid = threadIdx.x;
  if (row < 4096){
    const int tok = src[row];
    emb_src_bf[(size_t)row*256 + tid] = f2bf(embed[(size_t)tok*256 + tid]);
  } else {
    const int r = row - 4096;
    short v = 0;
    if (r < 992){ const int tok = trg[r]; v = f2bf(embed[(size_t)tok*256 + tid]); }
    emb_trg_bf[(size_t)r*256 + tid] = v;
  }
}

// ---------------------------------------------------------------------------
// MFMA GEMM: A_bf16 @ W_f32^T + biases. tmode: C_T[t][col][b]; Cbf: bf16 output
__global__ __launch_bounds__(256) void k_gemm_aw(
    const short* __restrict__ A, int lda,
    const float* __restrict__ W, int ldw,
    float* __restrict__ C, int ldc,
    const float* __restrict__ bias0, const float* __restrict__ bias1,
    int Mvalid, int K, int tmode, short* __restrict__ Cbf)
{
  __shared__ __align__(16) short As[128*32];
  __shared__ __align__(16) short Bs[128*32];
  const int tid = threadIdx.x;
  const int bm = blockIdx.x, bn = blockIdx.y;
  const int w  = tid >> 6,  l  = tid & 63;
  const int wm = w >> 1,    wn = w & 1;
  const int lr = l & 15,    lk = l >> 4;

  const int r0 = tid >> 2;
  const int s0 = (tid & 3) << 3;
  const int r1 = r0 + 64;

  const short* a0 = A + (size_t)(bm*128 + r0)*lda + s0;
  const short* a1 = A + (size_t)(bm*128 + r1)*lda + s0;
  const float* w0 = W + (size_t)(bn*128 + r0)*ldw + s0;
  const float* w1 = W + (size_t)(bn*128 + r1)*ldw + s0;

  const f32x4 zero4 = {0.f,0.f,0.f,0.f};
  f32x4 acc[4][4];
  #pragma unroll
  for (int mi=0;mi<4;mi++){
    #pragma unroll
    for (int ni=0;ni<4;ni++) acc[mi][ni] = zero4;
  }

  for (int k0 = 0; k0 < K; k0 += 32){
    short8 va0 = *(const short8*)(a0 + k0);
    short8 va1 = *(const short8*)(a1 + k0);
    float4 f00 = *(const float4*)(w0 + k0);
    float4 f01 = *(const float4*)(w0 + k0 + 4);
    float4 f10 = *(const float4*)(w1 + k0);
    float4 f11 = *(const float4*)(w1 + k0 + 4);
    short8 vb0, vb1;
    vb0[0]=f2bf(f00.x); vb0[1]=f2bf(f00.y); vb0[2]=f2bf(f00.z); vb0[3]=f2bf(f00.w);
    vb0[4]=f2bf(f01.x); vb0[5]=f2bf(f01.y); vb0[6]=f2bf(f01.z); vb0[7]=f2bf(f01.w);
    vb1[0]=f2bf(f10.x); vb1[1]=f2bf(f10.y); vb1[2]=f2bf(f10.z); vb1[3]=f2bf(f10.w);
    vb1[4]=f2bf(f11.x); vb1[5]=f2bf(f11.y); vb1[6]=f2bf(f11.z); vb1[7]=f2bf(f11.w);

    __syncthreads();
    *((short8*)As + tid)       = va0;
    *((short8*)As + tid + 256) = va1;
    *((short8*)Bs + tid)       = vb0;
    *((short8*)Bs + tid + 256) = vb1;
    __syncthreads();

    short8 af[4], bfr[4];
    #pragma unroll
    for (int mi=0;mi<4;mi++) af[mi]  = *(const short8*)&As[(wm*64 + mi*16 + lr)*32 + (lk<<3)];
    #pragma unroll
    for (int ni=0;ni<4;ni++) bfr[ni] = *(const short8*)&Bs[(wn*64 + ni*16 + lr)*32 + (lk<<3)];
    #pragma unroll
    for (int mi=0;mi<4;mi++){
      #pragma unroll
      for (int ni=0;ni<4;ni++)
        acc[mi][ni] = __builtin_amdgcn_mfma_f32_16x16x32_bf16(af[mi], bfr[ni], acc[mi][ni], 0,0,0);
    }
  }

  #pragma unroll
  for (int mi=0;mi<4;mi++){
    const int rb = bm*128 + wm*64 + mi*16 + (lk<<2);
    #pragma unroll
    for (int ni=0;ni<4;ni++){
      const int col = bn*128 + wn*64 + ni*16 + lr;
      float bv = 0.f;
      if (bias0) bv += bias0[col];
      if (bias1) bv += bias1[col];
      #pragma unroll
      for (int rr=0;rr<4;rr++){
        const int row = rb + rr;
        if (row < Mvalid){
          const float vv = acc[mi][ni][rr] + bv;
          if (Cbf)        Cbf[(size_t)row*ldc + col] = f2bf(vv);
          else if (tmode) C[(size_t)(row>>5)*65536 + (size_t)col*32 + (row&31)] = vv;
          else            C[(size_t)row*ldc + col] = vv;
        }
      }
    }
  }
}

// ---------------------------------------------------------------------------
// persistent bidirectional encoder, 256 blocks.
// x=bid&7, m=bid>>3: dir=m&1, bg=(m>>1)&3, jb=x*4+(m>>3)
// flags: fid = jb + 32*bg (per dir); consumer waits only its bg's 8 quads.
__global__ __launch_bounds__(256,1) void k_enc_persist(
    const float* __restrict__ pre_f, const float* __restrict__ pre_b,  // [128][2048][32] (+biases)
    const unsigned short* __restrict__ WhF, const unsigned short* __restrict__ WhB, // f16 [2048][512]
    float* __restrict__ f_outs, float* __restrict__ b_outs,            // [128][32][512]
    float* __restrict__ c_f_out, float* __restrict__ c_b_out,
    unsigned* __restrict__ flagF, unsigned* __restrict__ flagB)
{
  __shared__ __align__(16) unsigned x_lds[8*264];
  __shared__ float zbuf[64*8];
  const int bid = blockIdx.x, tid = threadIdx.x;
  const int x = bid & 7, m = bid >> 3;
  const int dir = m & 1, bg = (m >> 1) & 3, q = m >> 3;
  const int jb = x*4 + q;
  const float* pre = dir ? pre_b : pre_f;
  const unsigned* Wh = (const unsigned*)(dir ? WhB : WhF);
  float* outs = dir ? b_outs : f_outs;
  float* c_out = dir ? c_b_out : c_f_out;
  unsigned* flags = dir ? flagB : flagF;
  const int fid = jb + 32*bg;

  const int bb = tid & 7, rr = tid >> 3;
  const int g = rr >> 3, op = rr & 7;
  const unsigned* wA = Wh + (size_t)(g*512 + jb*16 + 2*op)*256;
  const unsigned* wB = wA + 256;

  const int fo = tid & 15, fb = tid >> 4;       // finish (tid<128)
  const int b_out = bg*8 + fb, k_out = jb*16 + fo;
  float c_reg = 0.f;

  for (int t = 0; t < 128; ++t){
    // prefetch pre[t] (independent of flags; latency hides under wait+stage+dot)
    float pz[4];
    if (tid < 128){
      const int tt = dir ? (127 - t) : t;
      const float* pt = pre + (size_t)tt*65536;
      #pragma unroll
      for (int gg = 0; gg < 4; ++gg)
        pz[gg] = pt[(size_t)(gg*512 + k_out)*32 + b_out];
    }
    if (t) wait_flags(flags + 32*bg, 8, (unsigned)t);
    if (t == 0){
      for (int i = tid; i < 8*264; i += 256) x_lds[i] = 0;
    } else {
      stage8b(outs + (size_t)(t-1)*16384 + (size_t)(bg*8)*512, x_lds, 264);
    }
    __syncthreads();

    const float2 d = dot2rows(x_lds + bb*264, wA, wB);
    zbuf[(g*16 + 2*op)*8 + bb]   = d.x;
    zbuf[(g*16 + 2*op+1)*8 + bb] = d.y;
    __syncthreads();

    if (tid < 128){
      float z[4];
      #pragma unroll
      for (int gg = 0; gg < 4; ++gg)
        z[gg] = pz[gg] + zbuf[(gg*16 + fo)*8 + fb];
      const float cn = sigmf(z[1])*c_reg + sigmf(z[0])*fast_tanh(z[2]);
      c_reg = cn;
      store_coh_f32(outs + (size_t)t*16384 + (size_t)b_out*512 + k_out, sigmf(z[3])*fast_tanh(cn));
    }
    set_flag(flags + fid, (unsigned)(t+1));
  }
  if (tid < 128) c_out[b_out*512 + k_out] = c_reg;
}

// ---------------------------------------------------------------------------
__global__ __launch_bounds__(256) void k_sum_enc(
    const float* __restrict__ f_outs, const float* __restrict__ b_outs,
    short* __restrict__ enc_sum_bf)
{
  const int i = blockIdx.x*256 + threadIdx.x;
  const int s = i >> 14, rem = i & 16383;
  enc_sum_bf[i] = f2bf(f_outs[i] + b_outs[(size_t)(127 - s)*16384 + rem]);
}

// ---------------------------------------------------------------------------
// persistent decoder, 256 blocks, 4 flag-synced phases/step.
// jb = (bid&7)*8 + ((bid>>3)>>2) in 0..63, bg = (bid>>3)&3; attn: blocks 0..31.
// flags: fid = bg*64 + jb; waits are on own bg's 16 quads only.
// P1: zh1=Whh1.h1[t-1], qs=Wq.h1[t-1]    (zh0 carried from P4 of t-1)
// P2: attn on 32 blocks
// P3: h0[t] = gates(demb + Wih0c.ctx + zh0)
// P4: h1[t] = gates(bias1 + Wih1.h0[t] + zh1); zh0' = Whh0.h0[t]
__global__ __launch_bounds__(256,1) void k_dec_persist(
    const float* __restrict__ demb,               // [32][2048][32] (+bih0+bhh0)
    const unsigned short* __restrict__ Wih0h,     // f16 [2048][512]
    const unsigned short* __restrict__ Whh0h,
    const unsigned short* __restrict__ Wih1h,
    const unsigned short* __restrict__ Whh1h,
    const float* __restrict__ bih1, const float* __restrict__ bhh1,
    const unsigned short* __restrict__ wqh,       // f16 [512][512]
    const float* __restrict__ attnV,
    const short* __restrict__ enc_proj_bf,        // [4096][512] (+attn_b)
    const short* __restrict__ enc_sum_bf,         // [4096][512]
    const float* __restrict__ h0_init, const float* __restrict__ h1_init,
    const float* __restrict__ c0_init, const float* __restrict__ c1_init,
    float* __restrict__ h0buf, float* __restrict__ h1buf,  // [2][32][512]
    float* __restrict__ ctxb,                              // [32][512]
    float* __restrict__ qsb,                               // [32][512]
    short* __restrict__ h1ctx,                             // [31][32][1024] bf16
    unsigned* __restrict__ dflag)
{
  __shared__ __align__(16) unsigned x0s[8*260];
  __shared__ __align__(16) unsigned x1s[8*260];
  __shared__ float zfin[32*9];
  __shared__ __align__(16) float q_s[512], v_s[512];
  __shared__ float part[256], aw[128], red[128];

  const int bid = blockIdx.x, tid = threadIdx.x;
  const int jb = (bid & 7)*8 + ((bid >> 3) >> 2);
  const int bg = (bid >> 3) & 3;
  const int fid = bg*64 + jb;
  unsigned* gq = dflag + bg*64;      // own-bg flag group (64 flags = 16 quads)

  const int b = tid & 7, r = tid >> 3;
  const int g = r >> 3, o = r & 7;
  const int j_row = g*512 + jb*8 + o;

  const int fo = tid & 7, fb = tid >> 3;        // finish (tid<64)
  const int b_out = bg*8 + fb, k_out = jb*8 + fo;

  const unsigned* Wh0row = (const unsigned*)Whh0h + (size_t)j_row*256;
  const unsigned* Wh1row = (const unsigned*)Whh1h + (size_t)j_row*256;
  const unsigned* Wi0row = (const unsigned*)Wih0h + (size_t)j_row*256;
  const unsigned* Wi1row = (const unsigned*)Wih1h + (size_t)j_row*256;
  const unsigned* Wqrow  = (const unsigned*)wqh  + (size_t)(jb*8 + b)*256;

  float c0_reg = 0.f, c1_reg = 0.f, bias1g[4];
  if (tid < 64){
    c0_reg = c0_init[b_out*512 + k_out];
    c1_reg = c1_init[b_out*512 + k_out];
    #pragma unroll
    for (int gg=0; gg<4; ++gg) bias1g[gg] = bih1[gg*512 + k_out] + bhh1[gg*512 + k_out];
  }
  if (bid < 32 && tid < 128) ((float4*)v_s)[tid] = ((const float4*)attnV)[tid];

  float zh0 = 0.f;

  for (int t = 0; t < 31; ++t){
    // prefetch demb[t] (used in P3; independent of flags)
    const float demb_v = demb[(size_t)t*65536 + (size_t)j_row*32 + bg*8 + b];

    // ---------------- P1: zh1 + qs from h1[t-1]  (zh0 carried) ----------------
    if (t){
      wait_flags(gq, 16, (unsigned)(4*t));
      stage8b(h1buf + (size_t)(t&1)*16384 + (size_t)(bg*8)*512, x1s, 260);
    } else {
      stage8b(h0_init + (size_t)(bg*8)*512, x0s, 260);
      stage8b(h1_init + (size_t)(bg*8)*512, x1s, 260);
    }
    __syncthreads();
    if (t == 0) zh0 = dot512(x0s + b*260, Wh0row);
    const float zh1 = dot512(x1s + b*260, Wh1row);
    if (tid < 64){
      const float qv = dot512(x1s + (tid>>3)*260, Wqrow);
      store_coh_f32(qsb + (size_t)(bg*8 + (tid>>3))*512 + jb*8 + b, qv);
    }

    // ---------------- P2: attention (blocks 0..31) ----------------
    if (bid < 32){
      set_flag(dflag + fid, (unsigned)(4*t+1));
      wait_flags(gq, 16, (unsigned)(4*t+1));
      const int ab = bid;
      if (tid < 128) ((float4*)q_s)[tid] = load_coh_f4(qsb + (size_t)ab*512 + (tid<<2));
      __syncthreads();
      {
        const int s = tid >> 1, half = tid & 1;
        const unsigned* ep = (const unsigned*)(enc_proj_bf + ((size_t)(s*32 + ab))*512 + (half << 8));
        const float* qh = q_s + (half << 8);
        const float* vh = v_s + (half << 8);
        float p = 0.f;
        for (int kk = 0; kk < 128; kk += 4){
          uint4 e = *(const uint4*)(ep + kk);
          const int k2 = kk << 1;
          p += fast_tanh(qh[k2+0] + bf2f_lo(e.x)) * vh[k2+0];
          p += fast_tanh(qh[k2+1] + bf2f_hi(e.x)) * vh[k2+1];
          p += fast_tanh(qh[k2+2] + bf2f_lo(e.y)) * vh[k2+2];
          p += fast_tanh(qh[k2+3] + bf2f_hi(e.y)) * vh[k2+3];
          p += fast_tanh(qh[k2+4] + bf2f_lo(e.z)) * vh[k2+4];
          p += fast_tanh(qh[k2+5] + bf2f_hi(e.z)) * vh[k2+5];
          p += fast_tanh(qh[k2+6] + bf2f_lo(e.w)) * vh[k2+6];
          p += fast_tanh(qh[k2+7] + bf2f_hi(e.w)) * vh[k2+7];
        }
        part[tid] = p;
      }
      __syncthreads();
      if (tid < 128){ const float sc = part[2*tid] + part[2*tid+1]; aw[tid] = sc; red[tid] = sc; }
      __syncthreads();
      for (int off = 64; off > 0; off >>= 1){
        if (tid < off) red[tid] = fmaxf(red[tid], red[tid+off]);
        __syncthreads();
      }
      const float mx = red[0];
      __syncthreads();
      if (tid < 128){ const float e = __expf(aw[tid] - mx); aw[tid] = e; red[tid] = e; }
      __syncthreads();
      for (int off = 64; off > 0; off >>= 1){
        if (tid < off) red[tid] += red[tid+off];
        __syncthreads();
      }
      const float inv = 1.0f / red[0];
      if (tid < 128) aw[tid] *= inv;
      __syncthreads();
      {
        const int cc = tid << 1;
        float x0 = 0.f, x1 = 0.f;
        for (int s2 = 0; s2 < 128; ++s2){
          const unsigned u = *(const unsigned*)(enc_sum_bf + ((size_t)(s2*32 + ab))*512 + cc);
          const float a = aw[s2];
          x0 = fmaf(a, bf2f_lo(u), x0);
          x1 = fmaf(a, bf2f_hi(u), x1);
        }
        store_coh_f32(ctxb + ab*512 + cc,     x0);
        store_coh_f32(ctxb + ab*512 + cc + 1, x1);
        h1ctx[(size_t)t*32768 + ab*1024 + 512 + cc]     = f2bf(x0);
        h1ctx[(size_t)t*32768 + ab*1024 + 512 + cc + 1] = f2bf(x1);
      }
      set_flag(dflag + fid, (unsigned)(4*t+2));
    } else {
      set_flag(dflag + fid, (unsigned)(4*t+2));   // also certifies this block's qs
    }

    // ---------------- P3: cell0 ----------------
    wait_flags(gq, 16, (unsigned)(4*t+2));
    stage8b(ctxb + (size_t)(bg*8)*512, x0s, 260);
    __syncthreads();
    {
      const float z = demb_v + dot512(x0s + b*260, Wi0row) + zh0;
      zfin[r*9 + b] = z;
    }
    __syncthreads();
    if (tid < 64){
      float z[4];
      #pragma unroll
      for (int gg=0; gg<4; ++gg) z[gg] = zfin[(gg*8 + fo)*9 + fb];
      const float cn = sigmf(z[1])*c0_reg + sigmf(z[0])*fast_tanh(z[2]);
      c0_reg = cn;
      store_coh_f32(h0buf + (size_t)((t+1)&1)*16384 + (size_t)b_out*512 + k_out,
                    sigmf(z[3])*fast_tanh(cn));
    }
    set_flag(dflag + fid, (unsigned)(4*t+3));

    // ---------------- P4: cell1 (+ zh0 for next step) ----------------
    wait_flags(gq, 16, (unsigned)(4*t+3));
    stage8b(h0buf + (size_t)((t+1)&1)*16384 + (size_t)(bg*8)*512, x1s, 260);
    __syncthreads();
    {
      const float z = dot512(x1s + b*260, Wi1row) + zh1;
      zh0 = dot512(x1s + b*260, Wh0row);          // for step t+1
      zfin[r*9 + b] = z;
    }
    __syncthreads();
    if (tid < 64){
      float z[4];
      #pragma unroll
      for (int gg=0; gg<4; ++gg) z[gg] = bias1g[gg] + zfin[(gg*8 + fo)*9 + fb];
      const float cn = sigmf(z[1])*c1_reg + sigmf(z[0])*fast_tanh(z[2]);
      c1_reg = cn;
      const float hn = sigmf(z[3])*fast_tanh(cn);
      store_coh_f32(h1buf + (size_t)((t+1)&1)*16384 + (size_t)b_out*512 + k_out, hn);
      h1ctx[(size_t)t*32768 + (size_t)b_out*1024 + k_out] = f2bf(hn);
    }
    set_flag(dflag + fid, (unsigned)(4*t+4));
  }
}

// ---------------------------------------------------------------------------
__global__ __launch_bounds__(256) void k_logsm(float* __restrict__ out){
  float* row = out + (size_t)blockIdx.x * 32000;
  const int tid = threadIdx.x;
  __shared__ float red[256];
  float m = -3.4e38f;
  for (int i = tid; i < 32000; i += 256) m = fmaxf(m, row[i]);
  red[tid] = m; __syncthreads();
  for (int off = 128; off > 0; off >>= 1){
    if (tid < off) red[tid] = fmaxf(red[tid], red[tid+off]);
    __syncthreads();
  }
  m = red[0]; __syncthreads();
  float s = 0.f;
  for (int i = tid; i < 32000; i += 256) s += __expf(row[i] - m);
  red[tid] = s; __syncthreads();
  for (int off = 128; off > 0; off >>= 1){
    if (tid < off) red[tid] += red[tid+off];
    __syncthreads();
  }
  const float lse = m + __logf(red[0]);
  for (int i = tid; i < 32000; i += 256) row[i] -= lse;
}

// ---------------------------------------------------------------------------
extern "C" void kernel_launch(void* const* d_in, const int* in_sizes, int n_in,
                              void* d_out, int out_size, void* d_ws, size_t ws_size,
                              hipStream_t stream)
{
  (void)in_sizes; (void)n_in; (void)out_size; (void)ws_size;
  const int*   src   = (const int*)d_in[0];
  const int*   trg   = (const int*)d_in[1];
  const float* embed = (const float*)d_in[2];
  const float* eWihF = (const float*)d_in[3];
  const float* eWhhF = (const float*)d_in[4];
  const float* ebihF = (const float*)d_in[5];
  const float* ebhhF = (const float*)d_in[6];
  const float* eWihB = (const float*)d_in[7];
  const float* eWhhB = (const float*)d_in[8];
  const float* ebihB = (const float*)d_in[9];
  const float* ebhhB = (const float*)d_in[10];
  const float* attnW = (const float*)d_in[11];
  const float* attnB = (const float*)d_in[12];
  const float* attnV = (const float*)d_in[13];
  const float* dWih0 = (const float*)d_in[14];
  const float* dWhh0 = (const float*)d_in[15];
  const float* dbih0 = (const float*)d_in[16];
  const float* dbhh0 = (const float*)d_in[17];
  const float* dWih1 = (const float*)d_in[18];
  const float* dWhh1 = (const float*)d_in[19];
  const float* dbih1 = (const float*)d_in[20];
  const float* dbhh1 = (const float*)d_in[21];
  const float* outW  = (const float*)d_in[22];
  const float* outB  = (const float*)d_in[23];

  float* out = (float*)d_out;
  // d_out scratch (all dead before final GEMM writes)
  float* enc_in_f = out;                         // [128][2048][32]
  float* enc_in_b = out + 8388608;
  short* enc_proj_bf = (short*)(out + 18874368); // [4096][512] bf16
  float* f_outs   = out + 20971520;              // [128][32][512]
  float* b_outs   = out + 23068672;
  float* demb     = out + 25165824;              // [32][2048][32]
  short* emb_src_bf = (short*)(out + 27262976);
  short* emb_trg_bf = (short*)(out + 27787264);
  short* enc_sum_bf = (short*)(out + 27918336);  // [4096][512] bf16
  unsigned short* wqh    = (unsigned short*)(out + 28966912);  // [512][512] f16
  unsigned short* whhF_h = (unsigned short*)(out + 29229056);  // each [2048][512] f16
  unsigned short* whhB_h = (unsigned short*)(out + 29753344);
  unsigned short* wih0_h = (unsigned short*)(out + 30277632);
  unsigned short* whh0_h = (unsigned short*)(out + 30801920);
  unsigned short* wih1_h = (unsigned short*)(out + 31326208);
  unsigned short* whh1_h = (unsigned short*)(out + 31850496);
  float* qsb            = out + 32374784;        // [32][512] f32

  char* ws = (char*)d_ws;
  short* h1ctx = (short*)ws;                     // [31][32][1024] bf16
  float* st    = (float*)(ws + 2097152);
  float* h0buf = st;                             // [2][32][512]
  float* h1buf = st + 32768;
  float* ctxb  = st + 65536;                     // [32][512]
  float* c_f   = st + 81920;
  float* c_b   = st + 98304;
  unsigned* flagF = (unsigned*)(st + 114688);    // 128
  unsigned* flagB = flagF + 128;                 // 128
  unsigned* dflag = flagF + 256;                 // 256

  // 1. zero flags
  k_zero<<<1, 256, 0, stream>>>((float*)flagF, 512);
  // 2. embedding gathers
  k_gather<<<5120, 256, 0, stream>>>(src, trg, embed, emb_src_bf, emb_trg_bf);
  // 3. batched input projections (transposed [t][j][b])
  {
    dim3 g1(32,16);
    k_gemm_aw<<<g1,256,0,stream>>>(emb_src_bf,256, eWihF,256, enc_in_f,2048, ebihF,ebhhF, 4096,256, 1, nullptr);
    k_gemm_aw<<<g1,256,0,stream>>>(emb_src_bf,256, eWihB,256, enc_in_b,2048, ebihB,ebhhB, 4096,256, 1, nullptr);
    dim3 g2(8,16);
    k_gemm_aw<<<g2,256,0,stream>>>(emb_trg_bf,256, dWih0,768, demb,2048, dbih0,dbhh0, 1024,256, 1, nullptr);
  }
  // 4. f16 weight conversions
  k_cvt_f16<<<1024,256,0,stream>>>(eWhhF, whhF_h, 1048576);
  k_cvt_f16<<<1024,256,0,stream>>>(eWhhB, whhB_h, 1048576);
  k_cvt_f16_str<<<1024,256,0,stream>>>(dWih0+256, 768, wih0_h, 1048576);
  k_cvt_f16<<<1024,256,0,stream>>>(dWhh0, whh0_h, 1048576);
  k_cvt_f16<<<1024,256,0,stream>>>(dWih1, wih1_h, 1048576);
  k_cvt_f16<<<1024,256,0,stream>>>(dWhh1, whh1_h, 1048576);
  k_cvt_f16_str<<<256,256,0,stream>>>(attnW, 1024, wqh, 262144);
  // 5. persistent encoder
  k_enc_persist<<<256, 256, 0, stream>>>(enc_in_f, enc_in_b, whhF_h, whhB_h,
                                         f_outs, b_outs, c_f, c_b, flagF, flagB);
  // 6. sum directions (bf16)
  k_sum_enc<<<8192, 256, 0, stream>>>(f_outs, b_outs, enc_sum_bf);
  // 7. attention enc projection (+attn_b), bf16 out
  {
    dim3 g3(32,4);
    k_gemm_aw<<<g3,256,0,stream>>>(enc_sum_bf,512, attnW+512,1024, nullptr,512, attnB,nullptr, 4096,512, 0, enc_proj_bf);
  }
  // 8. persistent decoder
  k_dec_persist<<<256, 256, 0, stream>>>(demb, wih0_h, whh0_h, wih1_h, whh1_h,
                                         dbih1, dbhh1, wqh, attnV, enc_proj_bf, enc_sum_bf,
                                         f_outs + (size_t)127*16384, b_outs + (size_t)127*16384,
                                         c_f, c_b, h0buf, h1buf, ctxb, qsb, h1ctx, dflag);
  // 9. outputs[0] = 0
  k_zero<<<512, 256, 0, stream>>>(out, 1024000);
  // 10. batched output projection
  {
    dim3 g4(8,250);
    k_gemm_aw<<<g4,256,0,stream>>>(h1ctx,1024, outW,1024, out + 1024000, 32000, outB,nullptr, 992,1024, 0, nullptr);
  }
  // 11. log_softmax
  k_logsm<<<992, 256, 0, stream>>>(out + 1024000);
}